// Round 1
// 1042.251 us; speedup vs baseline: 1.0356x; 1.0356x over previous
//
#include <hip/hip_runtime.h>

typedef _Float16 f16;
typedef f16  f16x8 __attribute__((ext_vector_type(8)));
typedef f16  f16x4 __attribute__((ext_vector_type(4)));
typedef float f32x4 __attribute__((ext_vector_type(4)));

#define LOAD_LDS16(gp, lp) __builtin_amdgcn_global_load_lds( \
    (const __attribute__((address_space(1))) void*)(gp),     \
    (__attribute__((address_space(3))) void*)(lp), 16, 0, 0)

// ---------------------------------------------------------------- helpers

__global__ __launch_bounds__(256) void castx_kernel(const float* __restrict__ x,
                                                    f16* __restrict__ o) {
  long i = ((long)blockIdx.x * 256 + threadIdx.x) * 4;
  const float4 v = *(const float4*)(x + i);
  f16x4 h; h.x = (f16)v.x; h.y = (f16)v.y; h.z = (f16)v.z; h.w = (f16)v.w;
  *(f16x4*)(o + i) = h;
}

// src [z][R][C] fp32  ->  dst (+z*dbatch) [c][r] fp16 with row stride dld
__global__ __launch_bounds__(256) void transpose_cast(const float* __restrict__ src,
                                                      f16* __restrict__ dst,
                                                      int R, int C, long sbatch,
                                                      long dbatch, int dld) {
  __shared__ float tile[32][33];
  const int zc = blockIdx.x * 32;
  const int zr = blockIdx.y * 32;
  const int z  = blockIdx.z;
  const float* s = src + (long)z * sbatch;
  f16* d = dst + (long)z * dbatch;
  const int tx = threadIdx.x & 31, ty = threadIdx.x >> 5;
#pragma unroll
  for (int rr = 0; rr < 32; rr += 8)
    tile[ty + rr][tx] = s[(long)(zr + ty + rr) * C + (zc + tx)];
  __syncthreads();
#pragma unroll
  for (int rr = 0; rr < 32; rr += 8)
    d[(long)(zc + ty + rr) * dld + (zr + tx)] = (f16)tile[tx][ty + rr];
}

// gating: logits, top-4-of-12 (lists + per-row slot map), softmax(6)+entropy.
__global__ __launch_bounds__(256) void gating_kernel(
    const float* __restrict__ x, const float* __restrict__ gaw,
    const float* __restrict__ gab, const float* __restrict__ ggw,
    const float* __restrict__ ggb,
    float* __restrict__ wG, float* __restrict__ ent,
    int* __restrict__ rows, float* __restrict__ gval, int* __restrict__ cnt,
    int* __restrict__ eA, int* __restrict__ posA, float* __restrict__ wA4) {
  const int b = blockIdx.x, t = threadIdx.x;
  const float* xr = x + (long)b * 1024;
  float pa[12], pg[6];
#pragma unroll
  for (int e = 0; e < 12; e++) pa[e] = 0.f;
#pragma unroll
  for (int e = 0; e < 6; e++) pg[e] = 0.f;
  const int i0 = t * 4;
  const float4 xv = *(const float4*)(xr + i0);
  const float xs[4] = {xv.x, xv.y, xv.z, xv.w};
#pragma unroll
  for (int u = 0; u < 4; u++) {
    const float xi = xs[u];
    const float* ga = gaw + (long)(i0 + u) * 12;
    const float* gg = ggw + (long)(i0 + u) * 6;
#pragma unroll
    for (int e = 0; e < 12; e++) pa[e] += xi * ga[e];
#pragma unroll
    for (int e = 0; e < 6; e++) pg[e] += xi * gg[e];
  }
#pragma unroll
  for (int e = 0; e < 12; e++)
    for (int m = 1; m < 64; m <<= 1) pa[e] += __shfl_xor(pa[e], m);
#pragma unroll
  for (int e = 0; e < 6; e++)
    for (int m = 1; m < 64; m <<= 1) pg[e] += __shfl_xor(pg[e], m);
  __shared__ float rw[4][18];
  const int lane = t & 63, wv = t >> 6;
  if (lane == 0) {
#pragma unroll
    for (int e = 0; e < 12; e++) rw[wv][e] = pa[e];
#pragma unroll
    for (int e = 0; e < 6; e++) rw[wv][12 + e] = pg[e];
  }
  __syncthreads();
  if (t == 0) {
    float la[12], lg[6];
#pragma unroll
    for (int e = 0; e < 12; e++)
      la[e] = rw[0][e] + rw[1][e] + rw[2][e] + rw[3][e] + gab[e];
#pragma unroll
    for (int e = 0; e < 6; e++)
      lg[e] = rw[0][12 + e] + rw[1][12 + e] + rw[2][12 + e] + rw[3][12 + e] + ggb[e];
    unsigned used = 0; float tv[4]; int tix[4];
    for (int k = 0; k < 4; k++) {
      float best = -3.4e38f; int bi = 0;
      for (int e = 0; e < 12; e++)
        if (!((used >> e) & 1u) && la[e] > best) { best = la[e]; bi = e; }
      tv[k] = best; tix[k] = bi; used |= 1u << bi;
    }
    const float mx = tv[0];
    float s = 0.f, w4[4];
    for (int k = 0; k < 4; k++) { w4[k] = expf(tv[k] - mx); s += w4[k]; }
    for (int k = 0; k < 4; k++) {
      const float w = w4[k] / s;
      const int e = tix[k];
      const int pos = atomicAdd(&cnt[e], 1);
      rows[e * 2048 + pos] = b;
      gval[e * 2048 + pos] = w;
      eA[b * 4 + k] = e;
      posA[b * 4 + k] = pos;
      wA4[b * 4 + k] = w;
    }
    float mg = lg[0];
    for (int e = 1; e < 6; e++) mg = fmaxf(mg, lg[e]);
    float sg = 0.f, wg6[6];
    for (int e = 0; e < 6; e++) { wg6[e] = expf(lg[e] - mg); sg += wg6[e]; }
    float H = 0.f;
    for (int e = 0; e < 6; e++) {
      const float w = wg6[e] / sg;
      wG[b * 6 + e] = w;
      H -= w * logf(w + 1e-8f);
    }
    ent[b] = H;
  }
}

__global__ void base_kernel(const int* __restrict__ cnt, int* __restrict__ baseA) {
  if (threadIdx.x == 0 && blockIdx.x == 0) {
    int r = 0;
    for (int e = 0; e < 12; e++) { baseA[e] = r; r += cnt[e]; }
  }
}

// combine: out_plus/out_minus from compact res + gate-weighted biases; tension0
__global__ __launch_bounds__(256) void combine_kernel(
    const f16* __restrict__ res, const int* __restrict__ eA,
    const int* __restrict__ posA, const float* __restrict__ wA4,
    const float* __restrict__ wG, const int* __restrict__ baseA,
    const float* __restrict__ ba2, const float* __restrict__ bg2,
    float* __restrict__ outP, float* __restrict__ outM,
    float* __restrict__ pt0, float* __restrict__ ts0) {
  const long b = blockIdx.x;
  const int t = threadIdx.x;
  const int c = t * 4;
  float4 P = {0.f, 0.f, 0.f, 0.f}, M = {0.f, 0.f, 0.f, 0.f};
#pragma unroll
  for (int k = 0; k < 4; k++) {
    const int e = eA[b * 4 + k];
    const long slot = baseA[e] + posA[b * 4 + k];
    const f16x4 v = *(const f16x4*)(res + slot * 1024 + c);
    const float w = wA4[b * 4 + k];
    const float4 bb = *(const float4*)(ba2 + (long)e * 1024 + c);
    P.x += (float)v.x + w * bb.x; P.y += (float)v.y + w * bb.y;
    P.z += (float)v.z + w * bb.z; P.w += (float)v.w + w * bb.w;
  }
#pragma unroll
  for (int e = 0; e < 6; e++) {
    const f16x4 v = *(const f16x4*)(res + (8192L + e * 2048 + b) * 1024 + c);
    const float w = wG[b * 6 + e];
    const float4 bb = *(const float4*)(bg2 + (long)e * 1024 + c);
    M.x += (float)v.x + w * bb.x; M.y += (float)v.y + w * bb.y;
    M.z += (float)v.z + w * bb.z; M.w += (float)v.w + w * bb.w;
  }
  *(float4*)(outP + b * 1024 + c) = P;
  *(float4*)(outM + b * 1024 + c) = M;
  const float dx = P.x - M.x, dy = P.y - M.y, dz = P.z - M.z, dw = P.w - M.w;
  float s = dx * dx + dy * dy + dz * dz + dw * dw;
#pragma unroll
  for (int m = 1; m < 64; m <<= 1) s += __shfl_xor(s, m);
  __shared__ float rw[4];
  if ((t & 63) == 0) rw[t >> 6] = s;
  __syncthreads();
  if (t == 0) {
    const float tot = rw[0] + rw[1] + rw[2] + rw[3];
    pt0[b] = tot;
    atomicAdd(ts0, tot);
  }
}

__global__ __launch_bounds__(256) void hsm_kernel(
    const float* __restrict__ pt, const float* __restrict__ tsum,
    const float* __restrict__ w1, const float* __restrict__ b1,
    f16* __restrict__ o, int step) {
  const int j = blockIdx.x * 256 + threadIdx.x;
  const int b0 = blockIdx.y * 64;
  const float u0 = w1[j], u1 = w1[2048 + j], u2 = w1[4096 + j], bb = b1[j];
  const float tm = tsum[0] * (1.f / 2048.f);
  const float st = (float)step * (1.f / 3.f);
#pragma unroll 4
  for (int r = 0; r < 64; r++) {
    const int b = b0 + r;
    const float t = pt[b];
    const float delta = (step == 0) ? 0.f : (t - tm);
    o[(long)b * 2048 + j] = (f16)tanhf(t * u0 + delta * u1 + st * u2 + bb);
  }
}

__global__ __launch_bounds__(256) void aux_kernel(const float* __restrict__ ent,
                                                  const float* __restrict__ tsum,
                                                  float* __restrict__ out) {
  const int t = threadIdx.x;
  float s = 0.f;
  for (int i = t; i < 2048; i += 256) s += ent[i];
#pragma unroll
  for (int m = 1; m < 64; m <<= 1) s += __shfl_xor(s, m);
  __shared__ float rw[4];
  if ((t & 63) == 0) rw[t >> 6] = s;
  __syncthreads();
  if (t == 0) {
    const float h = (rw[0] + rw[1] + rw[2] + rw[3]) * (1.f / 2048.f);
    const float d = h - 1.0114042647f;
    const float el = d * d;
    const float t0 = tsum[0] * (1.f / 2048.f), t1 = tsum[1] * (1.f / 2048.f);
    const float t2 = tsum[2] * (1.f / 2048.f), t3 = tsum[3] * (1.f / 2048.f);
    const float conv = (fabsf(t1 - t0) + fabsf(t2 - t1) + fabsf(t3 - t2)) * (1.f / 3.f);
    out[0] = el + 0.001f * conv;
  }
}

// ------------------------------------------------ unified GEMM1 (18 experts)
// h[row] = gate * relu(x[src_row] @ w1t[e18]^T + b1[e18]);  BM=128 BN=128 K=1024
// grid 4608: ids 0..3071 EngineA routed, 3072..4607 EngineG dense.
// LDS tiles are chunk-XOR-swizzled: physical 16B chunk = row*4 + (c ^ ((row>>1)&3)).
// global_load_lds dest stays LINEAR; the global SOURCE chunk is pre-swizzled,
// reads apply the same involution (rule: both-sides-or-neither).
__global__ __launch_bounds__(256) void gemm1_kernel(
    const f16* __restrict__ x, const f16* __restrict__ w1t,
    const float* __restrict__ ba1, const float* __restrict__ bg1,
    f16* __restrict__ h, const int* __restrict__ rows,
    const float* __restrict__ gval, const int* __restrict__ cnt,
    const int* __restrict__ baseA, const float* __restrict__ wG) {
  __shared__ f16 Al[2][128 * 32];
  __shared__ f16 Bl[2][128 * 32];
  __shared__ int   Lrow[128];
  __shared__ float Lg[128];
  int id = blockIdx.x;
  int e18, mi, ni, live; long row0; const float* bp;
  if (id < 3072) {                       // EngineA routed (XCD owns (e,n), m fast)
    const int k = id & 7, t = id >> 3;
    mi = t & 15; const int pid = k * 24 + (t >> 4);
    const int e = pid >> 4; ni = pid & 15;
    live = cnt[e] - mi * 128;
    if (live <= 0) return;
    if (live > 128) live = 128;
    row0 = baseA[e] + mi * 128; e18 = e; bp = ba1 + (long)e * 2048;
  } else {
    id -= 3072;
    const int k = id & 7, t = id >> 3;
    mi = t & 15; const int pid = k * 12 + (t >> 4);
    const int e = pid >> 4; ni = pid & 15;
    row0 = 8192L + e * 2048 + mi * 128; live = 128;
    e18 = 12 + e; bp = bg1 + (long)e * 2048;
  }
  const int tid = threadIdx.x;
  const bool routed = (e18 < 12);
  if (tid < 128) {
    const int gi = mi * 128 + tid;
    if (routed) {
      const bool ok = tid < live;
      Lrow[tid] = ok ? rows[e18 * 2048 + gi] : 0;
      Lg[tid]   = ok ? gval[e18 * 2048 + gi] : 0.f;
    } else {
      Lrow[tid] = gi;
      Lg[tid] = wG[gi * 6 + (e18 - 12)];
    }
  }
  __syncthreads();
  // pre-swizzled source chunk: row = tid>>2 (and row+64 -> same swizzle, period 8)
  const int sc = ((tid & 3) ^ ((tid >> 3) & 3)) * 8;
  const int r0 = Lrow[tid >> 2], r1 = Lrow[64 + (tid >> 2)];
  const f16* a0 = x + (long)r0 * 1024 + sc;
  const f16* a1 = x + (long)r1 * 1024 + sc;
  const f16* b0 = w1t + (long)e18 * 2048 * 1024 + ((long)ni * 128 + (tid >> 2)) * 1024 + sc;
  const f16* b1p = b0 + 64 * 1024;

  const int wave = tid >> 6, lane = tid & 63;
  const int wm = wave & 1, wn = wave >> 1;
  const int l16 = lane & 15, q = lane >> 4;
  // swizzled read chunk: row bits 1..2 come from l16 only (i*16, w*64 drop out)
  const int qa = (q ^ ((l16 >> 1) & 3)) * 8;
  f32x4 acc[4][4] = {};

  LOAD_LDS16(a0, &Al[0][tid * 8]);
  LOAD_LDS16(a1, &Al[0][(256 + tid) * 8]);
  LOAD_LDS16(b0, &Bl[0][tid * 8]);
  LOAD_LDS16(b1p, &Bl[0][(256 + tid) * 8]);
  for (int kk = 0; kk < 32; ++kk) {
    __syncthreads();
    const int cur = kk & 1;
    if (kk + 1 < 32) {
      const long k0 = (long)(kk + 1) * 32;
      const int nb = cur ^ 1;
      LOAD_LDS16(a0 + k0, &Al[nb][tid * 8]);
      LOAD_LDS16(a1 + k0, &Al[nb][(256 + tid) * 8]);
      LOAD_LDS16(b0 + k0, &Bl[nb][tid * 8]);
      LOAD_LDS16(b1p + k0, &Bl[nb][(256 + tid) * 8]);
    }
    f16x8 av[4], bv[4];
#pragma unroll
    for (int i = 0; i < 4; i++)
      av[i] = *(const f16x8*)&Al[cur][(wm * 64 + i * 16 + l16) * 32 + qa];
#pragma unroll
    for (int j = 0; j < 4; j++)
      bv[j] = *(const f16x8*)&Bl[cur][(wn * 64 + j * 16 + l16) * 32 + qa];
#pragma unroll
    for (int i = 0; i < 4; i++)
#pragma unroll
      for (int j = 0; j < 4; j++)
        acc[i][j] = __builtin_amdgcn_mfma_f32_16x16x32_f16(av[i], bv[j], acc[i][j], 0, 0, 0);
  }
  // epilogue: relu + gate, store h (row stride 2048)
#pragma unroll
  for (int i = 0; i < 4; i++) {
#pragma unroll
    for (int r = 0; r < 4; r++) {
      const int lr = wm * 64 + i * 16 + q * 4 + r;
      if (lr < live) {
        const float wv = Lg[lr];
        f16* C = h + (row0 + lr) * 2048;
#pragma unroll
        for (int j = 0; j < 4; j++) {
          const int gc = ni * 128 + wn * 64 + j * 16 + l16;
          const float v = fmaxf(acc[i][j][r] + bp[gc], 0.f) * wv;
          C[gc] = (f16)v;
        }
      }
    }
  }
}

// ------------------------------------------------ unified GEMM2 (18 experts)
// res[row] = h[row] @ w2t[e18]^T ; BM=128 BN=128 K=2048, plain f16 store
// grid 2304: ids 0..1535 EngineA routed, 1536..2303 EngineG dense.
__global__ __launch_bounds__(256) void gemm2_kernel(
    const f16* __restrict__ h, const f16* __restrict__ w2t,
    f16* __restrict__ res, const int* __restrict__ cnt,
    const int* __restrict__ baseA) {
  __shared__ f16 Al[2][128 * 32];
  __shared__ f16 Bl[2][128 * 32];
  int id = blockIdx.x;
  int e18, mi, ni, live; long row0;
  if (id < 1536) {                       // 12 exp * 16 mi * 8 ni, XCD owns (e,ni)
    const int k = id & 7, t = id >> 3;
    mi = t & 15; const int pid = k * 12 + (t >> 4);
    const int e = pid >> 3; ni = pid & 7;
    live = cnt[e] - mi * 128;
    if (live <= 0) return;
    if (live > 128) live = 128;
    row0 = baseA[e] + mi * 128; e18 = e;
  } else {
    id -= 1536;                          // 6 exp * 16 mi * 8 ni
    const int k = id & 7, t = id >> 3;
    mi = t & 15; const int pid = k * 6 + (t >> 4);
    const int e = pid >> 3; ni = pid & 7;
    row0 = 8192L + e * 2048 + mi * 128; live = 128; e18 = 12 + e;
  }
  const int tid = threadIdx.x;
  const int sc = ((tid & 3) ^ ((tid >> 3) & 3)) * 8;
  const f16* a0 = h + (row0 + (tid >> 2)) * 2048 + sc;
  const f16* a1 = a0 + 64 * 2048;
  const f16* b0 = w2t + (long)e18 * 1024 * 2048 + ((long)ni * 128 + (tid >> 2)) * 2048 + sc;
  const f16* b1p = b0 + 64 * 2048;

  const int wave = tid >> 6, lane = tid & 63;
  const int wm = wave & 1, wn = wave >> 1;
  const int l16 = lane & 15, q = lane >> 4;
  const int qa = (q ^ ((l16 >> 1) & 3)) * 8;
  f32x4 acc[4][4] = {};

  LOAD_LDS16(a0, &Al[0][tid * 8]);
  LOAD_LDS16(a1, &Al[0][(256 + tid) * 8]);
  LOAD_LDS16(b0, &Bl[0][tid * 8]);
  LOAD_LDS16(b1p, &Bl[0][(256 + tid) * 8]);
  for (int kk = 0; kk < 64; ++kk) {
    __syncthreads();
    const int cur = kk & 1;
    if (kk + 1 < 64) {
      const long k0 = (long)(kk + 1) * 32;
      const int nb = cur ^ 1;
      LOAD_LDS16(a0 + k0, &Al[nb][tid * 8]);
      LOAD_LDS16(a1 + k0, &Al[nb][(256 + tid) * 8]);
      LOAD_LDS16(b0 + k0, &Bl[nb][tid * 8]);
      LOAD_LDS16(b1p + k0, &Bl[nb][(256 + tid) * 8]);
    }
    f16x8 av[4], bv[4];
#pragma unroll
    for (int i = 0; i < 4; i++)
      av[i] = *(const f16x8*)&Al[cur][(wm * 64 + i * 16 + l16) * 32 + qa];
#pragma unroll
    for (int j = 0; j < 4; j++)
      bv[j] = *(const f16x8*)&Bl[cur][(wn * 64 + j * 16 + l16) * 32 + qa];
#pragma unroll
    for (int i = 0; i < 4; i++)
#pragma unroll
      for (int j = 0; j < 4; j++)
        acc[i][j] = __builtin_amdgcn_mfma_f32_16x16x32_f16(av[i], bv[j], acc[i][j], 0, 0, 0);
  }
#pragma unroll
  for (int i = 0; i < 4; i++) {
#pragma unroll
    for (int r = 0; r < 4; r++) {
      const int lr = wm * 64 + i * 16 + q * 4 + r;
      if (lr < live) {
        f16* C = res + (row0 + lr) * 1024 + ni * 128;
#pragma unroll
        for (int j = 0; j < 4; j++) {
          const int gc = wn * 64 + j * 16 + l16;
          C[gc] = (f16)acc[i][j][r];
        }
      }
    }
  }
}

// ------------------------------------------------ small dense GEMM (dbuf)

struct GA {
  const f16* A; long lda;
  const f16* B; long ldb;
  int nk;
  float* Cf; f16* Ch;
  const float* bias;
  const float* op; const float* om;
  const float* pt; const float* ts;
  float* pt_out; float* tsum_out;
};

// BM=BN=64. EPI: 2 tanh->f16 ; 3 mod+tension ; 4 final output
template <int EPI>
__global__ __launch_bounds__(256) void gemm_s(GA a) {
  __shared__ f16 Al[2][64 * 32];
  __shared__ f16 Bl[2][64 * 32];
  const int tid = threadIdx.x;
  const int wave = tid >> 6, lane = tid & 63;
  const int wm = wave & 1, wn = wave >> 1;
  const int l16 = lane & 15, q = lane >> 4;
  const int qa = (q ^ ((l16 >> 1) & 3)) * 8;
  const long m0 = (long)blockIdx.y * 64;
  const long n0 = (long)blockIdx.x * 64;
  const int sc = ((tid & 3) ^ ((tid >> 3) & 3)) * 8;
  const f16* a0 = a.A + (m0 + (tid >> 2)) * a.lda + sc;
  const f16* b0 = a.B + (n0 + (tid >> 2)) * a.ldb + sc;
  f32x4 acc[2][2] = {};
  LOAD_LDS16(a0, &Al[0][tid * 8]);
  LOAD_LDS16(b0, &Bl[0][tid * 8]);
  for (int kk = 0; kk < a.nk; ++kk) {
    __syncthreads();
    const int cur = kk & 1;
    if (kk + 1 < a.nk) {
      const long k0 = (long)(kk + 1) * 32;
      const int nb = cur ^ 1;
      LOAD_LDS16(a0 + k0, &Al[nb][tid * 8]);
      LOAD_LDS16(b0 + k0, &Bl[nb][tid * 8]);
    }
    f16x8 av[2], bv[2];
#pragma unroll
    for (int i = 0; i < 2; i++)
      av[i] = *(const f16x8*)&Al[cur][(wm * 32 + i * 16 + l16) * 32 + qa];
#pragma unroll
    for (int j = 0; j < 2; j++)
      bv[j] = *(const f16x8*)&Bl[cur][(wn * 32 + j * 16 + l16) * 32 + qa];
#pragma unroll
    for (int i = 0; i < 2; i++)
#pragma unroll
      for (int j = 0; j < 2; j++)
        acc[i][j] = __builtin_amdgcn_mfma_f32_16x16x32_f16(av[i], bv[j], acc[i][j], 0, 0, 0);
  }
  if constexpr (EPI == 2) {
#pragma unroll
    for (int i = 0; i < 2; i++)
#pragma unroll
      for (int r = 0; r < 4; r++) {
        const long gr = m0 + wm * 32 + i * 16 + q * 4 + r;
#pragma unroll
        for (int j = 0; j < 2; j++) {
          const int gc = (int)n0 + wn * 32 + j * 16 + l16;
          a.Ch[gr * 1024 + gc] = (f16)tanhf(acc[i][j][r] + a.bias[gc]);
        }
      }
  } else if constexpr (EPI == 3) {
    float wave_ss = 0.f;
#pragma unroll
    for (int i = 0; i < 2; i++)
#pragma unroll
      for (int r = 0; r < 4; r++) {
        const long gr = m0 + wm * 32 + i * 16 + q * 4 + r;
        float ss = 0.f;
#pragma unroll
        for (int j = 0; j < 2; j++) {
          const int gc = (int)n0 + wn * 32 + j * 16 + l16;
          const long ix = gr * 1024 + gc;
          const float v = (a.op[ix] - a.om[ix]) + acc[i][j][r] + a.bias[gc];
          a.Ch[ix] = (f16)v;
          ss += v * v;
        }
        ss += __shfl_xor(ss, 1); ss += __shfl_xor(ss, 2);
        ss += __shfl_xor(ss, 4); ss += __shfl_xor(ss, 8);
        if (l16 == 0) {
          atomicAdd(a.pt_out + gr, ss);
          wave_ss += ss;
        }
      }
    wave_ss += __shfl_xor(wave_ss, 16);
    wave_ss += __shfl_xor(wave_ss, 32);
    if (lane == 0) atomicAdd(a.tsum_out, wave_ss);
  } else {  // EPI == 4
    const float tsc = a.ts[0];
#pragma unroll
    for (int i = 0; i < 2; i++)
#pragma unroll
      for (int r = 0; r < 4; r++) {
        const long gr = m0 + wm * 32 + i * 16 + q * 4 + r;
        const float sq = sqrtf(a.pt[gr] + 1e-8f) * tsc;
#pragma unroll
        for (int j = 0; j < 2; j++) {
          const int gc = (int)n0 + wn * 32 + j * 16 + l16;
          const long ix = gr * 1024 + gc;
          const float v = tanhf(acc[i][j][r] + a.bias[gc]);
          a.Cf[ix] = 0.5f * (a.op[ix] + a.om[ix]) + sq * v;
        }
      }
  }
}

// ---------------------------------------------------------------- launcher

extern "C" void kernel_launch(void* const* d_in, const int* in_sizes, int n_in,
                              void* d_out, int out_size, void* d_ws, size_t ws_size,
                              hipStream_t stream) {
  (void)in_sizes; (void)n_in; (void)out_size; (void)ws_size;
  const float* x    = (const float*)d_in[0];
  const float* gaw  = (const float*)d_in[1];
  const float* gab  = (const float*)d_in[2];
  const float* wa1  = (const float*)d_in[3];
  const float* ba1  = (const float*)d_in[4];
  const float* wa2  = (const float*)d_in[5];
  const float* ba2  = (const float*)d_in[6];
  const float* ggw  = (const float*)d_in[7];
  const float* ggb  = (const float*)d_in[8];
  const float* wg1  = (const float*)d_in[9];
  const float* bg1  = (const float*)d_in[10];
  const float* wg2  = (const float*)d_in[11];
  const float* bg2  = (const float*)d_in[12];
  const float* smw1 = (const float*)d_in[13];
  const float* smb1 = (const float*)d_in[14];
  const float* smw2 = (const float*)d_in[15];
  const float* smb2 = (const float*)d_in[16];
  const float* siw  = (const float*)d_in[17];
  const float* sib  = (const float*)d_in[18];
  const float* ftw  = (const float*)d_in[19];
  const float* ftb  = (const float*)d_in[20];
  const float* tsc  = (const float*)d_in[21];

  char* p = (char*)d_ws;
  size_t off = 0;
  auto alloc = [&](size_t bytes) -> char* {
    char* r = p + off;
    off = (off + bytes + 255) & ~(size_t)255;
    return r;
  };
  f16* xb     = (f16*)alloc(2048UL * 1024 * 2);
  f16* w1t    = (f16*)alloc(18UL * 2048 * 1024 * 2);   // later reused as w2t
  f16* smw2t  = (f16*)alloc(1024UL * 2048 * 2);
  f16* sit    = (f16*)alloc(1024UL * 1024 * 2);
  f16* ftt    = (f16*)alloc(1024UL * 1024 * 2);
  f16* h      = (f16*)alloc(20480UL * 2048 * 2);       // 8192 A-compact + 6*2048 G
  f16* res    = (f16*)alloc(20480UL * 1024 * 2);
  float* outP = (float*)alloc(2048UL * 1024 * 4);
  float* outM = (float*)alloc(2048UL * 1024 * 4);
  f16* hsmb   = (f16*)alloc(2048UL * 2048 * 2);
  f16* sst    = (f16*)alloc(2048UL * 1024 * 2);
  f16* modb   = (f16*)alloc(2048UL * 1024 * 2);
  float* entb = (float*)alloc(2048 * 4);
  float* wGb  = (float*)alloc(2048 * 6 * 4);
  float* ptb  = (float*)alloc(4 * 2048 * 4);           // 32768 B
  float* tsb  = (float*)alloc(4 * 4);                  // +32768 (rounds to 256)
  int*   cntb = (int*)alloc(12 * 4);                   // +33024
  int*   baseAb = (int*)alloc(12 * 4);
  int*   rowsb  = (int*)alloc(12 * 2048 * 4);
  float* gvalb  = (float*)alloc(12 * 2048 * 4);
  int*   eAb    = (int*)alloc(2048 * 4 * 4);
  int*   posAb  = (int*)alloc(2048 * 4 * 4);
  float* wA4b   = (float*)alloc(2048 * 4 * 4);

  f16* w2t = w1t;  // [18][1024][2048], reused after gemm1

  // zero tension accumulators + expert counters (contiguous region)
  hipMemsetAsync(ptb, 0, 33072, stream);

  // weight conversion + transpose to [N][K] fp16
  transpose_cast<<<dim3(64, 32, 12), 256, 0, stream>>>(wa1, w1t, 1024, 2048,
      1024L * 2048, 2048L * 1024, 1024);
  transpose_cast<<<dim3(64, 32, 6), 256, 0, stream>>>(wg1, w1t + 12UL * 2048 * 1024,
      1024, 2048, 1024L * 2048, 2048L * 1024, 1024);
  transpose_cast<<<dim3(32, 64, 1), 256, 0, stream>>>(smw2, smw2t, 2048, 1024, 0, 0, 2048);
  transpose_cast<<<dim3(32, 32, 1), 256, 0, stream>>>(siw, sit, 1024, 1024, 0, 0, 1024);
  transpose_cast<<<dim3(32, 32, 1), 256, 0, stream>>>(ftw, ftt, 1024, 1024, 0, 0, 1024);
  castx_kernel<<<2048, 256, 0, stream>>>(x, xb);
  gating_kernel<<<2048, 256, 0, stream>>>(x, gaw, gab, ggw, ggb, wGb, entb,
                                          rowsb, gvalb, cntb, eAb, posAb, wA4b);
  base_kernel<<<1, 64, 0, stream>>>(cntb, baseAb);

  // unified GEMM1 (A routed + G dense), one dispatch
  gemm1_kernel<<<4608, 256, 0, stream>>>(xb, w1t, ba1, bg1, h,
                                         rowsb, gvalb, cntb, baseAb, wGb);

  // layer-2 weights into the (now dead) w1t region
  transpose_cast<<<dim3(32, 64, 12), 256, 0, stream>>>(wa2, w2t, 2048, 1024,
      2048L * 1024, 1024L * 2048, 2048);
  transpose_cast<<<dim3(32, 64, 6), 256, 0, stream>>>(wg2, w2t + 12UL * 1024 * 2048,
      2048, 1024, 2048L * 1024, 1024L * 2048, 2048);

  // unified GEMM2, compact f16 out, no atomics, BM=BN=128
  gemm2_kernel<<<2304, 256, 0, stream>>>(h, w2t, res, cntb, baseAb);

  combine_kernel<<<2048, 256, 0, stream>>>(res, eAb, posAb, wA4b, wGb, baseAb,
                                           ba2, bg2, outP, outM, ptb, tsb);

  for (int s = 0; s < 3; s++) {
    hsm_kernel<<<dim3(8, 32), 256, 0, stream>>>(ptb + s * 2048, tsb + s, smw1, smb1, hsmb, s);
    GA g3{};
    g3.A = hsmb; g3.lda = 2048; g3.B = smw2t; g3.ldb = 2048; g3.nk = 64;
    g3.Ch = sst; g3.bias = smb2;
    gemm_s<2><<<dim3(16, 32), 256, 0, stream>>>(g3);
    GA g4{};
    g4.A = sst; g4.lda = 1024; g4.B = sit; g4.ldb = 1024; g4.nk = 32;
    g4.Ch = modb; g4.bias = sib; g4.op = outP; g4.om = outM;
    g4.pt_out = ptb + (s + 1) * 2048; g4.tsum_out = tsb + (s + 1);
    gemm_s<3><<<dim3(16, 32), 256, 0, stream>>>(g4);
  }

  GA g5{};
  g5.A = modb; g5.lda = 1024; g5.B = ftt; g5.ldb = 1024; g5.nk = 32;
  g5.Cf = (float*)d_out; g5.bias = ftb; g5.op = outP; g5.om = outM;
  g5.pt = ptb + 3 * 2048; g5.ts = tsc;
  gemm_s<4><<<dim3(16, 32), 256, 0, stream>>>(g5);

  aux_kernel<<<1, 256, 0, stream>>>(entb, tsb, (float*)d_out + 2048UL * 1024);
}

// Round 2
// 1015.758 us; speedup vs baseline: 1.0626x; 1.0261x over previous
//
#include <hip/hip_runtime.h>

typedef _Float16 f16;
typedef f16  f16x8 __attribute__((ext_vector_type(8)));
typedef f16  f16x4 __attribute__((ext_vector_type(4)));
typedef float f32x4 __attribute__((ext_vector_type(4)));

#define LOAD_LDS16(gp, lp) __builtin_amdgcn_global_load_lds( \
    (const __attribute__((address_space(1))) void*)(gp),     \
    (__attribute__((address_space(3))) void*)(lp), 16, 0, 0)

// ---------------------------------------------------------------- helpers

// two-source batched transpose: z < zsplit reads s0, else s1.
// src [z][R][C] fp32 -> dst (+z*dbatch) [c][r] fp16 with row stride dld
__global__ __launch_bounds__(256) void transpose_cast2(const float* __restrict__ s0,
                                                       const float* __restrict__ s1,
                                                       int zsplit, f16* __restrict__ dst,
                                                       int R, int C, long sbatch,
                                                       long dbatch, int dld) {
  __shared__ float tile[32][33];
  const int zc = blockIdx.x * 32;
  const int zr = blockIdx.y * 32;
  const int z  = blockIdx.z;
  const float* s = (z < zsplit) ? (s0 + (long)z * sbatch)
                                : (s1 + (long)(z - zsplit) * sbatch);
  f16* d = dst + (long)z * dbatch;
  const int tx = threadIdx.x & 31, ty = threadIdx.x >> 5;
#pragma unroll
  for (int rr = 0; rr < 32; rr += 8)
    tile[ty + rr][tx] = s[(long)(zr + ty + rr) * C + (zc + tx)];
  __syncthreads();
#pragma unroll
  for (int rr = 0; rr < 32; rr += 8)
    d[(long)(zc + ty + rr) * dld + (zr + tx)] = (f16)tile[tx][ty + rr];
}

// three independent small transposes in one launch (descriptor per z)
struct TDesc { const float* s; f16* d; int R; int C; int dld; };
struct TDesc3 { TDesc m[3]; };

__global__ __launch_bounds__(256) void transpose3(TDesc3 p) {
  const TDesc t = p.m[blockIdx.z];
  const int zc = blockIdx.x * 32;
  const int zr = blockIdx.y * 32;
  if (zr >= t.R || zc >= t.C) return;   // block-uniform exit
  __shared__ float tile[32][33];
  const int tx = threadIdx.x & 31, ty = threadIdx.x >> 5;
#pragma unroll
  for (int rr = 0; rr < 32; rr += 8)
    tile[ty + rr][tx] = t.s[(long)(zr + ty + rr) * t.C + (zc + tx)];
  __syncthreads();
#pragma unroll
  for (int rr = 0; rr < 32; rr += 8)
    t.d[(long)(zc + ty + rr) * t.dld + (zr + tx)] = (f16)tile[tx][ty + rr];
}

// gating: logits, top-4-of-12 (lists + per-row slot map), softmax(6)+entropy.
// Also emits xb (f16 cast of x) — castx fused in since every element is read here.
__global__ __launch_bounds__(256) void gating_kernel(
    const float* __restrict__ x, const float* __restrict__ gaw,
    const float* __restrict__ gab, const float* __restrict__ ggw,
    const float* __restrict__ ggb, f16* __restrict__ xb,
    float* __restrict__ wG, float* __restrict__ ent,
    int* __restrict__ rows, float* __restrict__ gval, int* __restrict__ cnt,
    int* __restrict__ eA, int* __restrict__ posA, float* __restrict__ wA4) {
  const int b = blockIdx.x, t = threadIdx.x;
  const float* xr = x + (long)b * 1024;
  float pa[12], pg[6];
#pragma unroll
  for (int e = 0; e < 12; e++) pa[e] = 0.f;
#pragma unroll
  for (int e = 0; e < 6; e++) pg[e] = 0.f;
  const int i0 = t * 4;
  const float4 xv = *(const float4*)(xr + i0);
  f16x4 hx; hx.x = (f16)xv.x; hx.y = (f16)xv.y; hx.z = (f16)xv.z; hx.w = (f16)xv.w;
  *(f16x4*)(xb + (long)b * 1024 + i0) = hx;
  const float xs[4] = {xv.x, xv.y, xv.z, xv.w};
#pragma unroll
  for (int u = 0; u < 4; u++) {
    const float xi = xs[u];
    const float* ga = gaw + (long)(i0 + u) * 12;
    const float* gg = ggw + (long)(i0 + u) * 6;
#pragma unroll
    for (int e = 0; e < 12; e++) pa[e] += xi * ga[e];
#pragma unroll
    for (int e = 0; e < 6; e++) pg[e] += xi * gg[e];
  }
#pragma unroll
  for (int e = 0; e < 12; e++)
    for (int m = 1; m < 64; m <<= 1) pa[e] += __shfl_xor(pa[e], m);
#pragma unroll
  for (int e = 0; e < 6; e++)
    for (int m = 1; m < 64; m <<= 1) pg[e] += __shfl_xor(pg[e], m);
  __shared__ float rw[4][18];
  const int lane = t & 63, wv = t >> 6;
  if (lane == 0) {
#pragma unroll
    for (int e = 0; e < 12; e++) rw[wv][e] = pa[e];
#pragma unroll
    for (int e = 0; e < 6; e++) rw[wv][12 + e] = pg[e];
  }
  __syncthreads();
  if (t == 0) {
    float la[12], lg[6];
#pragma unroll
    for (int e = 0; e < 12; e++)
      la[e] = rw[0][e] + rw[1][e] + rw[2][e] + rw[3][e] + gab[e];
#pragma unroll
    for (int e = 0; e < 6; e++)
      lg[e] = rw[0][12 + e] + rw[1][12 + e] + rw[2][12 + e] + rw[3][12 + e] + ggb[e];
    unsigned used = 0; float tv[4]; int tix[4];
    for (int k = 0; k < 4; k++) {
      float best = -3.4e38f; int bi = 0;
      for (int e = 0; e < 12; e++)
        if (!((used >> e) & 1u) && la[e] > best) { best = la[e]; bi = e; }
      tv[k] = best; tix[k] = bi; used |= 1u << bi;
    }
    const float mx = tv[0];
    float s = 0.f, w4[4];
    for (int k = 0; k < 4; k++) { w4[k] = expf(tv[k] - mx); s += w4[k]; }
    for (int k = 0; k < 4; k++) {
      const float w = w4[k] / s;
      const int e = tix[k];
      const int pos = atomicAdd(&cnt[e], 1);
      rows[e * 2048 + pos] = b;
      gval[e * 2048 + pos] = w;
      eA[b * 4 + k] = e;
      posA[b * 4 + k] = pos;
      wA4[b * 4 + k] = w;
    }
    float mg = lg[0];
    for (int e = 1; e < 6; e++) mg = fmaxf(mg, lg[e]);
    float sg = 0.f, wg6[6];
    for (int e = 0; e < 6; e++) { wg6[e] = expf(lg[e] - mg); sg += wg6[e]; }
    float H = 0.f;
    for (int e = 0; e < 6; e++) {
      const float w = wg6[e] / sg;
      wG[b * 6 + e] = w;
      H -= w * logf(w + 1e-8f);
    }
    ent[b] = H;
  }
}

__global__ void base_kernel(const int* __restrict__ cnt, int* __restrict__ baseA) {
  if (threadIdx.x == 0 && blockIdx.x == 0) {
    int r = 0;
    for (int e = 0; e < 12; e++) { baseA[e] = r; r += cnt[e]; }
  }
}

// combine: out_plus/out_minus from compact res + gate-weighted biases; tension0
__global__ __launch_bounds__(256) void combine_kernel(
    const f16* __restrict__ res, const int* __restrict__ eA,
    const int* __restrict__ posA, const float* __restrict__ wA4,
    const float* __restrict__ wG, const int* __restrict__ baseA,
    const float* __restrict__ ba2, const float* __restrict__ bg2,
    float* __restrict__ outP, float* __restrict__ outM,
    float* __restrict__ pt0, float* __restrict__ ts0) {
  const long b = blockIdx.x;
  const int t = threadIdx.x;
  const int c = t * 4;
  float4 P = {0.f, 0.f, 0.f, 0.f}, M = {0.f, 0.f, 0.f, 0.f};
#pragma unroll
  for (int k = 0; k < 4; k++) {
    const int e = eA[b * 4 + k];
    const long slot = baseA[e] + posA[b * 4 + k];
    const f16x4 v = *(const f16x4*)(res + slot * 1024 + c);
    const float w = wA4[b * 4 + k];
    const float4 bb = *(const float4*)(ba2 + (long)e * 1024 + c);
    P.x += (float)v.x + w * bb.x; P.y += (float)v.y + w * bb.y;
    P.z += (float)v.z + w * bb.z; P.w += (float)v.w + w * bb.w;
  }
#pragma unroll
  for (int e = 0; e < 6; e++) {
    const f16x4 v = *(const f16x4*)(res + (8192L + e * 2048 + b) * 1024 + c);
    const float w = wG[b * 6 + e];
    const float4 bb = *(const float4*)(bg2 + (long)e * 1024 + c);
    M.x += (float)v.x + w * bb.x; M.y += (float)v.y + w * bb.y;
    M.z += (float)v.z + w * bb.z; M.w += (float)v.w + w * bb.w;
  }
  *(float4*)(outP + b * 1024 + c) = P;
  *(float4*)(outM + b * 1024 + c) = M;
  const float dx = P.x - M.x, dy = P.y - M.y, dz = P.z - M.z, dw = P.w - M.w;
  float s = dx * dx + dy * dy + dz * dz + dw * dw;
#pragma unroll
  for (int m = 1; m < 64; m <<= 1) s += __shfl_xor(s, m);
  __shared__ float rw[4];
  if ((t & 63) == 0) rw[t >> 6] = s;
  __syncthreads();
  if (t == 0) {
    const float tot = rw[0] + rw[1] + rw[2] + rw[3];
    pt0[b] = tot;
    atomicAdd(ts0, tot);
  }
}

__global__ __launch_bounds__(256) void hsm_kernel(
    const float* __restrict__ pt, const float* __restrict__ tsum,
    const float* __restrict__ w1, const float* __restrict__ b1,
    f16* __restrict__ o, int step) {
  const int j = blockIdx.x * 256 + threadIdx.x;
  const int b0 = blockIdx.y * 64;
  const float u0 = w1[j], u1 = w1[2048 + j], u2 = w1[4096 + j], bb = b1[j];
  const float tm = tsum[0] * (1.f / 2048.f);
  const float st = (float)step * (1.f / 3.f);
#pragma unroll 4
  for (int r = 0; r < 64; r++) {
    const int b = b0 + r;
    const float t = pt[b];
    const float delta = (step == 0) ? 0.f : (t - tm);
    o[(long)b * 2048 + j] = (f16)tanhf(t * u0 + delta * u1 + st * u2 + bb);
  }
}

// ------------------------------------------------ unified GEMM1 (18 experts)
// h[row] = gate * relu(x[src_row] @ w1t[e18]^T + b1[e18]);  BM=128 BN=128 K=1024
// grid 4608: ids 0..3071 EngineA routed, 3072..4607 EngineG dense.
// LDS tiles chunk-XOR-swizzled; global_load_lds dest LINEAR, source pre-swizzled,
// reads apply the same involution (both-sides-or-neither).
__global__ __launch_bounds__(256) void gemm1_kernel(
    const f16* __restrict__ x, const f16* __restrict__ w1t,
    const float* __restrict__ ba1, const float* __restrict__ bg1,
    f16* __restrict__ h, const int* __restrict__ rows,
    const float* __restrict__ gval, const int* __restrict__ cnt,
    const int* __restrict__ baseA, const float* __restrict__ wG) {
  __shared__ f16 Al[2][128 * 32];
  __shared__ f16 Bl[2][128 * 32];
  __shared__ int   Lrow[128];
  __shared__ float Lg[128];
  int id = blockIdx.x;
  int e18, mi, ni, live; long row0; const float* bp;
  if (id < 3072) {                       // EngineA routed (XCD owns (e,n), m fast)
    const int k = id & 7, t = id >> 3;
    mi = t & 15; const int pid = k * 24 + (t >> 4);
    const int e = pid >> 4; ni = pid & 15;
    live = cnt[e] - mi * 128;
    if (live <= 0) return;
    if (live > 128) live = 128;
    row0 = baseA[e] + mi * 128; e18 = e; bp = ba1 + (long)e * 2048;
  } else {
    id -= 3072;
    const int k = id & 7, t = id >> 3;
    mi = t & 15; const int pid = k * 12 + (t >> 4);
    const int e = pid >> 4; ni = pid & 15;
    row0 = 8192L + e * 2048 + mi * 128; live = 128;
    e18 = 12 + e; bp = bg1 + (long)e * 2048;
  }
  const int tid = threadIdx.x;
  const bool routed = (e18 < 12);
  if (tid < 128) {
    const int gi = mi * 128 + tid;
    if (routed) {
      const bool ok = tid < live;
      Lrow[tid] = ok ? rows[e18 * 2048 + gi] : 0;
      Lg[tid]   = ok ? gval[e18 * 2048 + gi] : 0.f;
    } else {
      Lrow[tid] = gi;
      Lg[tid] = wG[gi * 6 + (e18 - 12)];
    }
  }
  __syncthreads();
  // pre-swizzled source chunk: row = tid>>2 (row+64 same swizzle, period 8)
  const int sc = ((tid & 3) ^ ((tid >> 3) & 3)) * 8;
  const int r0 = Lrow[tid >> 2], r1 = Lrow[64 + (tid >> 2)];
  const f16* a0 = x + (long)r0 * 1024 + sc;
  const f16* a1 = x + (long)r1 * 1024 + sc;
  const f16* b0 = w1t + (long)e18 * 2048 * 1024 + ((long)ni * 128 + (tid >> 2)) * 1024 + sc;
  const f16* b1p = b0 + 64 * 1024;

  const int wave = tid >> 6, lane = tid & 63;
  const int wm = wave & 1, wn = wave >> 1;
  const int l16 = lane & 15, q = lane >> 4;
  const int qa = (q ^ ((l16 >> 1) & 3)) * 8;
  f32x4 acc[4][4] = {};

  LOAD_LDS16(a0, &Al[0][tid * 8]);
  LOAD_LDS16(a1, &Al[0][(256 + tid) * 8]);
  LOAD_LDS16(b0, &Bl[0][tid * 8]);
  LOAD_LDS16(b1p, &Bl[0][(256 + tid) * 8]);
  for (int kk = 0; kk < 32; ++kk) {
    __syncthreads();
    const int cur = kk & 1;
    if (kk + 1 < 32) {
      const long k0 = (long)(kk + 1) * 32;
      const int nb = cur ^ 1;
      LOAD_LDS16(a0 + k0, &Al[nb][tid * 8]);
      LOAD_LDS16(a1 + k0, &Al[nb][(256 + tid) * 8]);
      LOAD_LDS16(b0 + k0, &Bl[nb][tid * 8]);
      LOAD_LDS16(b1p + k0, &Bl[nb][(256 + tid) * 8]);
    }
    f16x8 av[4], bv[4];
#pragma unroll
    for (int i = 0; i < 4; i++)
      av[i] = *(const f16x8*)&Al[cur][(wm * 64 + i * 16 + l16) * 32 + qa];
#pragma unroll
    for (int j = 0; j < 4; j++)
      bv[j] = *(const f16x8*)&Bl[cur][(wn * 64 + j * 16 + l16) * 32 + qa];
#pragma unroll
    for (int i = 0; i < 4; i++)
#pragma unroll
      for (int j = 0; j < 4; j++)
        acc[i][j] = __builtin_amdgcn_mfma_f32_16x16x32_f16(av[i], bv[j], acc[i][j], 0, 0, 0);
  }
  // epilogue: relu + gate, store h (row stride 2048)
#pragma unroll
  for (int i = 0; i < 4; i++) {
#pragma unroll
    for (int r = 0; r < 4; r++) {
      const int lr = wm * 64 + i * 16 + q * 4 + r;
      if (lr < live) {
        const float wv = Lg[lr];
        f16* C = h + (row0 + lr) * 2048;
#pragma unroll
        for (int j = 0; j < 4; j++) {
          const int gc = ni * 128 + wn * 64 + j * 16 + l16;
          const float v = fmaxf(acc[i][j][r] + bp[gc], 0.f) * wv;
          C[gc] = (f16)v;
        }
      }
    }
  }
}

// ------------------------------------------------ unified GEMM2 (18 experts)
// res[row] = h[row] @ w2t[e18]^T ; BM=128 BN=128 K=2048, plain f16 store
// grid 2304: ids 0..1535 EngineA routed, 1536..2303 EngineG dense.
__global__ __launch_bounds__(256) void gemm2_kernel(
    const f16* __restrict__ h, const f16* __restrict__ w2t,
    f16* __restrict__ res, const int* __restrict__ cnt,
    const int* __restrict__ baseA) {
  __shared__ f16 Al[2][128 * 32];
  __shared__ f16 Bl[2][128 * 32];
  int id = blockIdx.x;
  int e18, mi, ni, live; long row0;
  if (id < 1536) {                       // 12 exp * 16 mi * 8 ni, XCD owns (e,ni)
    const int k = id & 7, t = id >> 3;
    mi = t & 15; const int pid = k * 12 + (t >> 4);
    const int e = pid >> 3; ni = pid & 7;
    live = cnt[e] - mi * 128;
    if (live <= 0) return;
    if (live > 128) live = 128;
    row0 = baseA[e] + mi * 128; e18 = e;
  } else {
    id -= 1536;                          // 6 exp * 16 mi * 8 ni
    const int k = id & 7, t = id >> 3;
    mi = t & 15; const int pid = k * 6 + (t >> 4);
    const int e = pid >> 3; ni = pid & 7;
    row0 = 8192L + e * 2048 + mi * 128; live = 128; e18 = 12 + e;
  }
  const int tid = threadIdx.x;
  const int sc = ((tid & 3) ^ ((tid >> 3) & 3)) * 8;
  const f16* a0 = h + (row0 + (tid >> 2)) * 2048 + sc;
  const f16* a1 = a0 + 64 * 2048;
  const f16* b0 = w2t + (long)e18 * 1024 * 2048 + ((long)ni * 128 + (tid >> 2)) * 2048 + sc;
  const f16* b1p = b0 + 64 * 2048;

  const int wave = tid >> 6, lane = tid & 63;
  const int wm = wave & 1, wn = wave >> 1;
  const int l16 = lane & 15, q = lane >> 4;
  const int qa = (q ^ ((l16 >> 1) & 3)) * 8;
  f32x4 acc[4][4] = {};

  LOAD_LDS16(a0, &Al[0][tid * 8]);
  LOAD_LDS16(a1, &Al[0][(256 + tid) * 8]);
  LOAD_LDS16(b0, &Bl[0][tid * 8]);
  LOAD_LDS16(b1p, &Bl[0][(256 + tid) * 8]);
  for (int kk = 0; kk < 64; ++kk) {
    __syncthreads();
    const int cur = kk & 1;
    if (kk + 1 < 64) {
      const long k0 = (long)(kk + 1) * 32;
      const int nb = cur ^ 1;
      LOAD_LDS16(a0 + k0, &Al[nb][tid * 8]);
      LOAD_LDS16(a1 + k0, &Al[nb][(256 + tid) * 8]);
      LOAD_LDS16(b0 + k0, &Bl[nb][tid * 8]);
      LOAD_LDS16(b1p + k0, &Bl[nb][(256 + tid) * 8]);
    }
    f16x8 av[4], bv[4];
#pragma unroll
    for (int i = 0; i < 4; i++)
      av[i] = *(const f16x8*)&Al[cur][(wm * 64 + i * 16 + l16) * 32 + qa];
#pragma unroll
    for (int j = 0; j < 4; j++)
      bv[j] = *(const f16x8*)&Bl[cur][(wn * 64 + j * 16 + l16) * 32 + qa];
#pragma unroll
    for (int i = 0; i < 4; i++)
#pragma unroll
      for (int j = 0; j < 4; j++)
        acc[i][j] = __builtin_amdgcn_mfma_f32_16x16x32_f16(av[i], bv[j], acc[i][j], 0, 0, 0);
  }
#pragma unroll
  for (int i = 0; i < 4; i++) {
#pragma unroll
    for (int r = 0; r < 4; r++) {
      const int lr = wm * 64 + i * 16 + q * 4 + r;
      if (lr < live) {
        f16* C = res + (row0 + lr) * 1024 + ni * 128;
#pragma unroll
        for (int j = 0; j < 4; j++) {
          const int gc = wn * 64 + j * 16 + l16;
          C[gc] = (f16)acc[i][j][r];
        }
      }
    }
  }
}

// ------------------------------------------------ small dense GEMM (dbuf)
// BK=64: halves barrier count vs BK=32 (g3: 64->32 steps, g4/g5: 32->16).
// LDS rows are 128 B; chunk swizzle: phys = (hf*4+q) ^ (row&7), staged via
// pre-swizzled global source (linear LDS dest), read with same involution.

struct GA {
  const f16* A; long lda;
  const f16* B; long ldb;
  int nk;                      // K / 64
  float* Cf; f16* Ch;
  const float* bias;
  const float* op; const float* om;
  const float* pt; const float* ts;
  float* pt_out; float* tsum_out;
  const float* ent; const float* tsb; float* aux_out;  // EPI==4 aux fusion
};

// BM=BN=64. EPI: 2 tanh->f16 ; 3 mod+tension ; 4 final output (+aux in block 0,0)
template <int EPI>
__global__ __launch_bounds__(256) void gemm_s(GA a) {
  __shared__ f16 Al[2][64 * 64];
  __shared__ f16 Bl[2][64 * 64];
  const int tid = threadIdx.x;
  const int wave = tid >> 6, lane = tid & 63;
  const int wm = wave & 1, wn = wave >> 1;
  const int l16 = lane & 15, q = lane >> 4;
  const long m0 = (long)blockIdx.y * 64;
  const long n0 = (long)blockIdx.x * 64;
  // staging: thread t -> row = t>>3 (and +32), chunk = t&7, source pre-swizzled
  const int srow = tid >> 3;
  const int sch  = ((tid & 7) ^ (srow & 7)) * 8;
  const f16* a0 = a.A + (m0 + srow) * a.lda + sch;
  const f16* a1 = a.A + (m0 + srow + 32) * a.lda + sch;  // (srow+32)&7 == srow&7
  const f16* b0 = a.B + (n0 + srow) * a.ldb + sch;
  const f16* b1 = a.B + (n0 + srow + 32) * a.ldb + sch;
  const int rx = (l16 & 7) * 8;  // read-side XOR term (f16 units)
  f32x4 acc[2][2] = {};
  LOAD_LDS16(a0, &Al[0][tid * 8]);
  LOAD_LDS16(a1, &Al[0][(256 + tid) * 8]);
  LOAD_LDS16(b0, &Bl[0][tid * 8]);
  LOAD_LDS16(b1, &Bl[0][(256 + tid) * 8]);
  for (int kk = 0; kk < a.nk; ++kk) {
    __syncthreads();
    const int cur = kk & 1;
    if (kk + 1 < a.nk) {
      const long k0 = (long)(kk + 1) * 64;
      const int nb = cur ^ 1;
      LOAD_LDS16(a0 + k0, &Al[nb][tid * 8]);
      LOAD_LDS16(a1 + k0, &Al[nb][(256 + tid) * 8]);
      LOAD_LDS16(b0 + k0, &Bl[nb][tid * 8]);
      LOAD_LDS16(b1 + k0, &Bl[nb][(256 + tid) * 8]);
    }
    f16x8 av[2][2], bv[2][2];
#pragma unroll
    for (int hf = 0; hf < 2; hf++) {
      const int cA = (((hf * 4 + q) * 8) ^ rx);
#pragma unroll
      for (int i = 0; i < 2; i++)
        av[hf][i] = *(const f16x8*)&Al[cur][(wm * 32 + i * 16 + l16) * 64 + cA];
#pragma unroll
      for (int j = 0; j < 2; j++)
        bv[hf][j] = *(const f16x8*)&Bl[cur][(wn * 32 + j * 16 + l16) * 64 + cA];
    }
#pragma unroll
    for (int hf = 0; hf < 2; hf++)
#pragma unroll
      for (int i = 0; i < 2; i++)
#pragma unroll
        for (int j = 0; j < 2; j++)
          acc[i][j] = __builtin_amdgcn_mfma_f32_16x16x32_f16(av[hf][i], bv[hf][j], acc[i][j], 0, 0, 0);
  }
  if constexpr (EPI == 2) {
#pragma unroll
    for (int i = 0; i < 2; i++)
#pragma unroll
      for (int r = 0; r < 4; r++) {
        const long gr = m0 + wm * 32 + i * 16 + q * 4 + r;
#pragma unroll
        for (int j = 0; j < 2; j++) {
          const int gc = (int)n0 + wn * 32 + j * 16 + l16;
          a.Ch[gr * 1024 + gc] = (f16)tanhf(acc[i][j][r] + a.bias[gc]);
        }
      }
  } else if constexpr (EPI == 3) {
    float wave_ss = 0.f;
#pragma unroll
    for (int i = 0; i < 2; i++)
#pragma unroll
      for (int r = 0; r < 4; r++) {
        const long gr = m0 + wm * 32 + i * 16 + q * 4 + r;
        float ss = 0.f;
#pragma unroll
        for (int j = 0; j < 2; j++) {
          const int gc = (int)n0 + wn * 32 + j * 16 + l16;
          const long ix = gr * 1024 + gc;
          const float v = (a.op[ix] - a.om[ix]) + acc[i][j][r] + a.bias[gc];
          a.Ch[ix] = (f16)v;
          ss += v * v;
        }
        ss += __shfl_xor(ss, 1); ss += __shfl_xor(ss, 2);
        ss += __shfl_xor(ss, 4); ss += __shfl_xor(ss, 8);
        if (l16 == 0) {
          atomicAdd(a.pt_out + gr, ss);
          wave_ss += ss;
        }
      }
    wave_ss += __shfl_xor(wave_ss, 16);
    wave_ss += __shfl_xor(wave_ss, 32);
    if (lane == 0) atomicAdd(a.tsum_out, wave_ss);
  } else {  // EPI == 4
    const float tsc = a.ts[0];
#pragma unroll
    for (int i = 0; i < 2; i++)
#pragma unroll
      for (int r = 0; r < 4; r++) {
        const long gr = m0 + wm * 32 + i * 16 + q * 4 + r;
        const float sq = sqrtf(a.pt[gr] + 1e-8f) * tsc;
#pragma unroll
        for (int j = 0; j < 2; j++) {
          const int gc = (int)n0 + wn * 32 + j * 16 + l16;
          const long ix = gr * 1024 + gc;
          const float v = tanhf(acc[i][j][r] + a.bias[gc]);
          a.Cf[ix] = 0.5f * (a.op[ix] + a.om[ix]) + sq * v;
        }
      }
    // aux loss fused into block (0,0): all tsb[0..3] were written before launch
    if (blockIdx.x == 0 && blockIdx.y == 0) {
      float s = 0.f;
      for (int i = tid; i < 2048; i += 256) s += a.ent[i];
#pragma unroll
      for (int m = 1; m < 64; m <<= 1) s += __shfl_xor(s, m);
      __shared__ float rwa[4];
      if ((tid & 63) == 0) rwa[tid >> 6] = s;
      __syncthreads();
      if (tid == 0) {
        const float hh = (rwa[0] + rwa[1] + rwa[2] + rwa[3]) * (1.f / 2048.f);
        const float dd = hh - 1.0114042647f;
        const float el = dd * dd;
        const float t0 = a.tsb[0] * (1.f / 2048.f), t1 = a.tsb[1] * (1.f / 2048.f);
        const float t2 = a.tsb[2] * (1.f / 2048.f), t3 = a.tsb[3] * (1.f / 2048.f);
        const float conv = (fabsf(t1 - t0) + fabsf(t2 - t1) + fabsf(t3 - t2)) * (1.f / 3.f);
        a.aux_out[0] = el + 0.001f * conv;
      }
    }
  }
}

// ---------------------------------------------------------------- launcher

extern "C" void kernel_launch(void* const* d_in, const int* in_sizes, int n_in,
                              void* d_out, int out_size, void* d_ws, size_t ws_size,
                              hipStream_t stream) {
  (void)in_sizes; (void)n_in; (void)out_size; (void)ws_size;
  const float* x    = (const float*)d_in[0];
  const float* gaw  = (const float*)d_in[1];
  const float* gab  = (const float*)d_in[2];
  const float* wa1  = (const float*)d_in[3];
  const float* ba1  = (const float*)d_in[4];
  const float* wa2  = (const float*)d_in[5];
  const float* ba2  = (const float*)d_in[6];
  const float* ggw  = (const float*)d_in[7];
  const float* ggb  = (const float*)d_in[8];
  const float* wg1  = (const float*)d_in[9];
  const float* bg1  = (const float*)d_in[10];
  const float* wg2  = (const float*)d_in[11];
  const float* bg2  = (const float*)d_in[12];
  const float* smw1 = (const float*)d_in[13];
  const float* smb1 = (const float*)d_in[14];
  const float* smw2 = (const float*)d_in[15];
  const float* smb2 = (const float*)d_in[16];
  const float* siw  = (const float*)d_in[17];
  const float* sib  = (const float*)d_in[18];
  const float* ftw  = (const float*)d_in[19];
  const float* ftb  = (const float*)d_in[20];
  const float* tsc  = (const float*)d_in[21];

  char* p = (char*)d_ws;
  size_t off = 0;
  auto alloc = [&](size_t bytes) -> char* {
    char* r = p + off;
    off = (off + bytes + 255) & ~(size_t)255;
    return r;
  };
  f16* xb     = (f16*)alloc(2048UL * 1024 * 2);
  f16* w1t    = (f16*)alloc(18UL * 2048 * 1024 * 2);   // later reused as w2t
  f16* smw2t  = (f16*)alloc(1024UL * 2048 * 2);
  f16* sit    = (f16*)alloc(1024UL * 1024 * 2);
  f16* ftt    = (f16*)alloc(1024UL * 1024 * 2);
  f16* h      = (f16*)alloc(20480UL * 2048 * 2);       // 8192 A-compact + 6*2048 G
  f16* res    = (f16*)alloc(20480UL * 1024 * 2);
  float* outP = (float*)alloc(2048UL * 1024 * 4);
  float* outM = (float*)alloc(2048UL * 1024 * 4);
  f16* hsmb   = (f16*)alloc(2048UL * 2048 * 2);
  f16* sst    = (f16*)alloc(2048UL * 1024 * 2);
  f16* modb   = (f16*)alloc(2048UL * 1024 * 2);
  float* entb = (float*)alloc(2048 * 4);
  float* wGb  = (float*)alloc(2048 * 6 * 4);
  float* ptb  = (float*)alloc(4 * 2048 * 4);           // 32768 B
  float* tsb  = (float*)alloc(4 * 4);                  // +32768 (rounds to 256)
  int*   cntb = (int*)alloc(12 * 4);                   // +33024
  int*   baseAb = (int*)alloc(12 * 4);
  int*   rowsb  = (int*)alloc(12 * 2048 * 4);
  float* gvalb  = (float*)alloc(12 * 2048 * 4);
  int*   eAb    = (int*)alloc(2048 * 4 * 4);
  int*   posAb  = (int*)alloc(2048 * 4 * 4);
  float* wA4b   = (float*)alloc(2048 * 4 * 4);

  f16* w2t = w1t;  // [18][1024][2048], reused after gemm1

  // zero tension accumulators + expert counters (contiguous region)
  hipMemsetAsync(ptb, 0, 33072, stream);

  // weight conversion + transpose to [N][K] fp16 (wa1+wg1 in ONE launch)
  transpose_cast2<<<dim3(64, 32, 18), 256, 0, stream>>>(wa1, wg1, 12, w1t,
      1024, 2048, 1024L * 2048, 2048L * 1024, 1024);
  // the three small transposes in ONE launch
  {
    TDesc3 td;
    td.m[0] = {smw2, smw2t, 2048, 1024, 2048};
    td.m[1] = {siw,  sit,  1024, 1024, 1024};
    td.m[2] = {ftw,  ftt,  1024, 1024, 1024};
    transpose3<<<dim3(32, 64, 3), 256, 0, stream>>>(td);
  }
  gating_kernel<<<2048, 256, 0, stream>>>(x, gaw, gab, ggw, ggb, xb, wGb, entb,
                                          rowsb, gvalb, cntb, eAb, posAb, wA4b);
  base_kernel<<<1, 64, 0, stream>>>(cntb, baseAb);

  // unified GEMM1 (A routed + G dense), one dispatch
  gemm1_kernel<<<4608, 256, 0, stream>>>(xb, w1t, ba1, bg1, h,
                                         rowsb, gvalb, cntb, baseAb, wGb);

  // layer-2 weights into the (now dead) w1t region (wa2+wg2 in ONE launch)
  transpose_cast2<<<dim3(32, 64, 18), 256, 0, stream>>>(wa2, wg2, 12, w2t,
      2048, 1024, 2048L * 1024, 1024L * 2048, 2048);

  // unified GEMM2, compact f16 out, no atomics, BM=BN=128
  gemm2_kernel<<<2304, 256, 0, stream>>>(h, w2t, res, cntb, baseAb);

  combine_kernel<<<2048, 256, 0, stream>>>(res, eAb, posAb, wA4b, wGb, baseAb,
                                           ba2, bg2, outP, outM, ptb, tsb);

  for (int s = 0; s < 3; s++) {
    hsm_kernel<<<dim3(8, 32), 256, 0, stream>>>(ptb + s * 2048, tsb + s, smw1, smb1, hsmb, s);
    GA g3{};
    g3.A = hsmb; g3.lda = 2048; g3.B = smw2t; g3.ldb = 2048; g3.nk = 32;
    g3.Ch = sst; g3.bias = smb2;
    gemm_s<2><<<dim3(16, 32), 256, 0, stream>>>(g3);
    GA g4{};
    g4.A = sst; g4.lda = 1024; g4.B = sit; g4.ldb = 1024; g4.nk = 16;
    g4.Ch = modb; g4.bias = sib; g4.op = outP; g4.om = outM;
    g4.pt_out = ptb + (s + 1) * 2048; g4.tsum_out = tsb + (s + 1);
    gemm_s<3><<<dim3(16, 32), 256, 0, stream>>>(g4);
  }

  GA g5{};
  g5.A = modb; g5.lda = 1024; g5.B = ftt; g5.ldb = 1024; g5.nk = 16;
  g5.Cf = (float*)d_out; g5.bias = ftb; g5.op = outP; g5.om = outM;
  g5.pt = ptb + 3 * 2048; g5.ts = tsc;
  g5.ent = entb; g5.tsb = tsb; g5.aux_out = (float*)d_out + 2048UL * 1024;
  gemm_s<4><<<dim3(16, 32), 256, 0, stream>>>(g5);
}

// Round 3
// 999.464 us; speedup vs baseline: 1.0799x; 1.0163x over previous
//
#include <hip/hip_runtime.h>

typedef _Float16 f16;
typedef f16  f16x8 __attribute__((ext_vector_type(8)));
typedef f16  f16x4 __attribute__((ext_vector_type(4)));
typedef float f32x4 __attribute__((ext_vector_type(4)));

#define LOAD_LDS16(gp, lp) __builtin_amdgcn_global_load_lds( \
    (const __attribute__((address_space(1))) void*)(gp),     \
    (__attribute__((address_space(3))) void*)(lp), 16, 0, 0)

// ---------------- 8-phase GEMM machinery (kernel-local names expected:
// NKC, Al, Bl, tid, pa0, pa1, pb0, pb1, arow, brow, qa, av, bv, acc)
#define BARX() __builtin_amdgcn_s_barrier()
#define SB0() __builtin_amdgcn_sched_barrier(0)
#define WLG0() asm volatile("s_waitcnt lgkmcnt(0)" ::: "memory")
#define WVM8() asm volatile("s_waitcnt vmcnt(8)" ::: "memory")
#define WVM0() asm volatile("s_waitcnt vmcnt(0)" ::: "memory")

// stage one 256x32 region (2 loads/thread). TT clamped at tail so the
// vmcnt(8) position-count stays exact; clamped stages land in free regions.
#define ST_A(TT, BB, KH) { \
  const long ko_ = (long)((TT) < NKC ? (TT) : (NKC - 1)) * 64 + (KH) * 32; \
  LOAD_LDS16(pa0 + ko_, &Al[BB][KH][tid * 8]); \
  LOAD_LDS16(pa1 + ko_, &Al[BB][KH][(512 + tid) * 8]); }
#define ST_B(TT, BB, KH) { \
  const long ko_ = (long)((TT) < NKC ? (TT) : (NKC - 1)) * 64 + (KH) * 32; \
  LOAD_LDS16(pb0 + ko_, &Bl[BB][KH][tid * 8]); \
  LOAD_LDS16(pb1 + ko_, &Bl[BB][KH][(512 + tid) * 8]); }

#define RD_AV(BB, KH) _Pragma("unroll") \
  for (int i_ = 0; i_ < 8; i_++) \
    av[i_] = *(const f16x8*)&Al[BB][KH][(arow + i_ * 16) * 32 + qa];
#define RD_BV(BB, KH, CB) _Pragma("unroll") \
  for (int j_ = 0; j_ < 2; j_++) \
    bv[j_] = *(const f16x8*)&Bl[BB][KH][(brow + (CB) * 32 + j_ * 16) * 32 + qa];
#define MF16(CB) \
  __builtin_amdgcn_s_setprio(1); \
  _Pragma("unroll") \
  for (int i_ = 0; i_ < 8; i_++) { \
    acc[i_][2 * (CB)]     = __builtin_amdgcn_mfma_f32_16x16x32_f16(av[i_], bv[0], acc[i_][2 * (CB)], 0, 0, 0); \
    acc[i_][2 * (CB) + 1] = __builtin_amdgcn_mfma_f32_16x16x32_f16(av[i_], bv[1], acc[i_][2 * (CB) + 1], 0, 0, 0); \
  } \
  __builtin_amdgcn_s_setprio(0);

// one K-tile (BK=64) = 4 phases. Stages: kh1 of tile KT+1 (phases 0,1),
// kh0 of tile KT+2 (phases 2,3). vmcnt(8) at phases 1,3 guards the reads
// happening 1-2 phases later (8 loads issued since the guarded stage).
#define GTILE(KT, BUF) { \
  RD_AV(BUF, 0) RD_BV(BUF, 0, 0) \
  ST_A((KT) + 1, (BUF) ^ 1, 1) \
  BARX(); WLG0(); SB0(); \
  MF16(0) \
  SB0(); BARX(); \
  RD_BV(BUF, 0, 1) \
  ST_B((KT) + 1, (BUF) ^ 1, 1) \
  WVM8(); \
  BARX(); WLG0(); SB0(); \
  MF16(1) \
  SB0(); BARX(); \
  RD_AV(BUF, 1) RD_BV(BUF, 1, 0) \
  ST_A((KT) + 2, (BUF), 0) \
  BARX(); WLG0(); SB0(); \
  MF16(0) \
  SB0(); BARX(); \
  RD_BV(BUF, 1, 1) \
  ST_B((KT) + 2, (BUF), 0) \
  WVM8(); \
  BARX(); WLG0(); SB0(); \
  MF16(1) \
  SB0(); BARX(); \
}

// ---------------------------------------------------------------- helpers

// two-source batched transpose: z < zsplit reads s0, else s1.
// src [z][R][C] fp32 -> dst (+z*dbatch) [c][r] fp16 with row stride dld
__global__ __launch_bounds__(256) void transpose_cast2(const float* __restrict__ s0,
                                                       const float* __restrict__ s1,
                                                       int zsplit, f16* __restrict__ dst,
                                                       int R, int C, long sbatch,
                                                       long dbatch, int dld) {
  __shared__ float tile[32][33];
  const int zc = blockIdx.x * 32;
  const int zr = blockIdx.y * 32;
  const int z  = blockIdx.z;
  const float* s = (z < zsplit) ? (s0 + (long)z * sbatch)
                                : (s1 + (long)(z - zsplit) * sbatch);
  f16* d = dst + (long)z * dbatch;
  const int tx = threadIdx.x & 31, ty = threadIdx.x >> 5;
#pragma unroll
  for (int rr = 0; rr < 32; rr += 8)
    tile[ty + rr][tx] = s[(long)(zr + ty + rr) * C + (zc + tx)];
  __syncthreads();
#pragma unroll
  for (int rr = 0; rr < 32; rr += 8)
    d[(long)(zc + ty + rr) * dld + (zr + tx)] = (f16)tile[tx][ty + rr];
}

// three independent small transposes in one launch (descriptor per z)
struct TDesc { const float* s; f16* d; int R; int C; int dld; };
struct TDesc3 { TDesc m[3]; };

__global__ __launch_bounds__(256) void transpose3(TDesc3 p) {
  const TDesc t = p.m[blockIdx.z];
  const int zc = blockIdx.x * 32;
  const int zr = blockIdx.y * 32;
  if (zr >= t.R || zc >= t.C) return;   // block-uniform exit
  __shared__ float tile[32][33];
  const int tx = threadIdx.x & 31, ty = threadIdx.x >> 5;
#pragma unroll
  for (int rr = 0; rr < 32; rr += 8)
    tile[ty + rr][tx] = t.s[(long)(zr + ty + rr) * t.C + (zc + tx)];
  __syncthreads();
#pragma unroll
  for (int rr = 0; rr < 32; rr += 8)
    t.d[(long)(zc + ty + rr) * t.dld + (zr + tx)] = (f16)tile[tx][ty + rr];
}

// gating: logits, top-4-of-12 (lists + per-row slot map), softmax(6)+entropy.
// Also emits xb (f16 cast of x) — castx fused in since every element is read here.
__global__ __launch_bounds__(256) void gating_kernel(
    const float* __restrict__ x, const float* __restrict__ gaw,
    const float* __restrict__ gab, const float* __restrict__ ggw,
    const float* __restrict__ ggb, f16* __restrict__ xb,
    float* __restrict__ wG, float* __restrict__ ent,
    int* __restrict__ rows, float* __restrict__ gval, int* __restrict__ cnt,
    int* __restrict__ eA, int* __restrict__ posA, float* __restrict__ wA4) {
  const int b = blockIdx.x, t = threadIdx.x;
  const float* xr = x + (long)b * 1024;
  float pa[12], pg[6];
#pragma unroll
  for (int e = 0; e < 12; e++) pa[e] = 0.f;
#pragma unroll
  for (int e = 0; e < 6; e++) pg[e] = 0.f;
  const int i0 = t * 4;
  const float4 xv = *(const float4*)(xr + i0);
  f16x4 hx; hx.x = (f16)xv.x; hx.y = (f16)xv.y; hx.z = (f16)xv.z; hx.w = (f16)xv.w;
  *(f16x4*)(xb + (long)b * 1024 + i0) = hx;
  const float xs[4] = {xv.x, xv.y, xv.z, xv.w};
#pragma unroll
  for (int u = 0; u < 4; u++) {
    const float xi = xs[u];
    const float* ga = gaw + (long)(i0 + u) * 12;
    const float* gg = ggw + (long)(i0 + u) * 6;
#pragma unroll
    for (int e = 0; e < 12; e++) pa[e] += xi * ga[e];
#pragma unroll
    for (int e = 0; e < 6; e++) pg[e] += xi * gg[e];
  }
#pragma unroll
  for (int e = 0; e < 12; e++)
    for (int m = 1; m < 64; m <<= 1) pa[e] += __shfl_xor(pa[e], m);
#pragma unroll
  for (int e = 0; e < 6; e++)
    for (int m = 1; m < 64; m <<= 1) pg[e] += __shfl_xor(pg[e], m);
  __shared__ float rw[4][18];
  const int lane = t & 63, wv = t >> 6;
  if (lane == 0) {
#pragma unroll
    for (int e = 0; e < 12; e++) rw[wv][e] = pa[e];
#pragma unroll
    for (int e = 0; e < 6; e++) rw[wv][12 + e] = pg[e];
  }
  __syncthreads();
  if (t == 0) {
    float la[12], lg[6];
#pragma unroll
    for (int e = 0; e < 12; e++)
      la[e] = rw[0][e] + rw[1][e] + rw[2][e] + rw[3][e] + gab[e];
#pragma unroll
    for (int e = 0; e < 6; e++)
      lg[e] = rw[0][12 + e] + rw[1][12 + e] + rw[2][12 + e] + rw[3][12 + e] + ggb[e];
    unsigned used = 0; float tv[4]; int tix[4];
    for (int k = 0; k < 4; k++) {
      float best = -3.4e38f; int bi = 0;
      for (int e = 0; e < 12; e++)
        if (!((used >> e) & 1u) && la[e] > best) { best = la[e]; bi = e; }
      tv[k] = best; tix[k] = bi; used |= 1u << bi;
    }
    const float mx = tv[0];
    float s = 0.f, w4[4];
    for (int k = 0; k < 4; k++) { w4[k] = expf(tv[k] - mx); s += w4[k]; }
    for (int k = 0; k < 4; k++) {
      const float w = w4[k] / s;
      const int e = tix[k];
      const int pos = atomicAdd(&cnt[e], 1);
      rows[e * 2048 + pos] = b;
      gval[e * 2048 + pos] = w;
      eA[b * 4 + k] = e;
      posA[b * 4 + k] = pos;
      wA4[b * 4 + k] = w;
    }
    float mg = lg[0];
    for (int e = 1; e < 6; e++) mg = fmaxf(mg, lg[e]);
    float sg = 0.f, wg6[6];
    for (int e = 0; e < 6; e++) { wg6[e] = expf(lg[e] - mg); sg += wg6[e]; }
    float H = 0.f;
    for (int e = 0; e < 6; e++) {
      const float w = wg6[e] / sg;
      wG[b * 6 + e] = w;
      H -= w * logf(w + 1e-8f);
    }
    ent[b] = H;
  }
}

__global__ void base_kernel(const int* __restrict__ cnt, int* __restrict__ baseA) {
  if (threadIdx.x == 0 && blockIdx.x == 0) {
    int r = 0;
    for (int e = 0; e < 12; e++) { baseA[e] = r; r += cnt[e]; }
  }
}

// combine: out_plus/out_minus from compact res + gate-weighted biases; tension0
__global__ __launch_bounds__(256) void combine_kernel(
    const f16* __restrict__ res, const int* __restrict__ eA,
    const int* __restrict__ posA, const float* __restrict__ wA4,
    const float* __restrict__ wG, const int* __restrict__ baseA,
    const float* __restrict__ ba2, const float* __restrict__ bg2,
    float* __restrict__ outP, float* __restrict__ outM,
    float* __restrict__ pt0, float* __restrict__ ts0) {
  const long b = blockIdx.x;
  const int t = threadIdx.x;
  const int c = t * 4;
  float4 P = {0.f, 0.f, 0.f, 0.f}, M = {0.f, 0.f, 0.f, 0.f};
#pragma unroll
  for (int k = 0; k < 4; k++) {
    const int e = eA[b * 4 + k];
    const long slot = baseA[e] + posA[b * 4 + k];
    const f16x4 v = *(const f16x4*)(res + slot * 1024 + c);
    const float w = wA4[b * 4 + k];
    const float4 bb = *(const float4*)(ba2 + (long)e * 1024 + c);
    P.x += (float)v.x + w * bb.x; P.y += (float)v.y + w * bb.y;
    P.z += (float)v.z + w * bb.z; P.w += (float)v.w + w * bb.w;
  }
#pragma unroll
  for (int e = 0; e < 6; e++) {
    const f16x4 v = *(const f16x4*)(res + (8192L + e * 2048 + b) * 1024 + c);
    const float w = wG[b * 6 + e];
    const float4 bb = *(const float4*)(bg2 + (long)e * 1024 + c);
    M.x += (float)v.x + w * bb.x; M.y += (float)v.y + w * bb.y;
    M.z += (float)v.z + w * bb.z; M.w += (float)v.w + w * bb.w;
  }
  *(float4*)(outP + b * 1024 + c) = P;
  *(float4*)(outM + b * 1024 + c) = M;
  const float dx = P.x - M.x, dy = P.y - M.y, dz = P.z - M.z, dw = P.w - M.w;
  float s = dx * dx + dy * dy + dz * dz + dw * dw;
#pragma unroll
  for (int m = 1; m < 64; m <<= 1) s += __shfl_xor(s, m);
  __shared__ float rw[4];
  if ((t & 63) == 0) rw[t >> 6] = s;
  __syncthreads();
  if (t == 0) {
    const float tot = rw[0] + rw[1] + rw[2] + rw[3];
    pt0[b] = tot;
    atomicAdd(ts0, tot);
  }
}

__global__ __launch_bounds__(256) void hsm_kernel(
    const float* __restrict__ pt, const float* __restrict__ tsum,
    const float* __restrict__ w1, const float* __restrict__ b1,
    f16* __restrict__ o, int step) {
  const int j = blockIdx.x * 256 + threadIdx.x;
  const int b0 = blockIdx.y * 64;
  const float u0 = w1[j], u1 = w1[2048 + j], u2 = w1[4096 + j], bb = b1[j];
  const float tm = tsum[0] * (1.f / 2048.f);
  const float st = (float)step * (1.f / 3.f);
#pragma unroll 4
  for (int r = 0; r < 64; r++) {
    const int b = b0 + r;
    const float t = pt[b];
    const float delta = (step == 0) ? 0.f : (t - tm);
    o[(long)b * 2048 + j] = (f16)tanhf(t * u0 + delta * u1 + st * u2 + bb);
  }
}

// ------------------------------------------------ unified GEMM1 (18 experts)
// h[row] = gate * relu(x[src_row] @ w1t[e18]^T + b1[e18])
// 8-phase schedule: BM=BN=256, BK=64, 8 waves, 128 KiB LDS, counted vmcnt(8).
// grid 1152: ids 0..767 EngineA routed, 768..1151 EngineG dense.
__global__ __launch_bounds__(512, 2) void gemm1_kernel(
    const f16* __restrict__ x, const f16* __restrict__ w1t,
    const float* __restrict__ ba1, const float* __restrict__ bg1,
    f16* __restrict__ h, const int* __restrict__ rows,
    const float* __restrict__ gval, const int* __restrict__ cnt,
    const int* __restrict__ baseA, const float* __restrict__ wG) {
  constexpr int NKC = 16;                 // K=1024 / 64
  __shared__ f16 Al[2][2][8192];          // [dbuf][khalf][256 rows x 32 cols]
  __shared__ f16 Bl[2][2][8192];
  __shared__ int   Lrow[256];
  __shared__ float Lg[256];
  int id = blockIdx.x;
  int e18, mi, ni, live; long row0; const float* bp;
  if (id < 768) {                         // EngineA routed, XCD owns (e,ni)
    const int k = id & 7, t = id >> 3;
    mi = t & 7; const int pid = k * 12 + (t >> 3);
    const int e = pid >> 3; ni = pid & 7;
    live = cnt[e] - mi * 256;
    if (live <= 0) return;
    if (live > 256) live = 256;
    row0 = baseA[e] + mi * 256; e18 = e; bp = ba1 + (long)e * 2048;
  } else {
    id -= 768;
    const int k = id & 7, t = id >> 3;
    mi = t & 7; const int pid = k * 6 + (t >> 3);
    const int e = pid >> 3; ni = pid & 7;
    row0 = 8192L + e * 2048 + mi * 256; live = 256;
    e18 = 12 + e; bp = bg1 + (long)e * 2048;
  }
  const int tid = threadIdx.x;
  const bool routed = (e18 < 12);
  if (tid < 256) {
    const int gi = mi * 256 + tid;
    if (routed) {
      const bool ok = tid < live;
      Lrow[tid] = ok ? rows[e18 * 2048 + gi] : 0;
      Lg[tid]   = ok ? gval[e18 * 2048 + gi] : 0.f;
    } else {
      Lrow[tid] = gi;
      Lg[tid] = wG[gi * 6 + (e18 - 12)];
    }
  }
  __syncthreads();                        // also drains vmcnt before staging
  const int srow = tid >> 2;
  const int sch = ((tid & 3) ^ ((tid >> 3) & 3)) * 8;  // pre-swizzled source chunk
  const f16* pa0 = x + (long)Lrow[srow] * 1024 + sch;
  const f16* pa1 = x + (long)Lrow[128 + srow] * 1024 + sch;
  const f16* pb0 = w1t + (long)e18 * 2048 * 1024 + ((long)ni * 256 + srow) * 1024 + sch;
  const f16* pb1 = pb0 + 128 * 1024;
  const int wave = tid >> 6, lane = tid & 63;
  const int wm = wave & 1, wn = wave >> 1;
  const int l16 = lane & 15, q = lane >> 4;
  const int qa = (q ^ ((l16 >> 1) & 3)) * 8;
  const int arow = wm * 128 + l16;
  const int brow = wn * 64 + l16;
  f32x4 acc[8][4] = {};
  f16x8 av[8], bv[2];
  // prologue: tile0 (all 4 regions) + tile1 kh0; oldest 4 loads drained
  ST_A(0, 0, 0) ST_B(0, 0, 0) ST_A(0, 0, 1) ST_B(0, 0, 1) ST_A(1, 1, 0) ST_B(1, 1, 0)
  WVM8(); BARX(); SB0();
#pragma unroll 1
  for (int kt = 0; kt < NKC; kt += 2) { GTILE(kt, 0) GTILE(kt + 1, 1) }
  WVM0();
  // epilogue: relu + gate + bias, store h (row stride 2048)
#pragma unroll
  for (int i = 0; i < 8; i++) {
#pragma unroll
    for (int r = 0; r < 4; r++) {
      const int lr = wm * 128 + i * 16 + q * 4 + r;
      if (lr < live) {
        const float wv = Lg[lr];
        f16* C = h + (row0 + lr) * 2048 + ni * 256;
#pragma unroll
        for (int jj = 0; jj < 4; jj++) {
          const int cc = wn * 64 + jj * 16 + l16;
          const float v = fmaxf(acc[i][jj][r] + bp[ni * 256 + cc], 0.f) * wv;
          C[cc] = (f16)v;
        }
      }
    }
  }
}

// ------------------------------------------------ unified GEMM2 (18 experts)
// res[row] = h[row] @ w2t[e18]^T ; 8-phase, BM=BN=256, BK=64, K=2048
// grid 576: ids 0..383 EngineA routed, 384..575 EngineG dense.
__global__ __launch_bounds__(512, 2) void gemm2_kernel(
    const f16* __restrict__ h, const f16* __restrict__ w2t,
    f16* __restrict__ res, const int* __restrict__ cnt,
    const int* __restrict__ baseA) {
  constexpr int NKC = 32;                 // K=2048 / 64
  __shared__ f16 Al[2][2][8192];
  __shared__ f16 Bl[2][2][8192];
  int id = blockIdx.x;
  int e18, mi, ni, live; long row0;
  if (id < 384) {                         // 12 exp * 8 mi * 4 ni
    const int k = id & 7, t = id >> 3;
    mi = t & 7; const int pid = k * 6 + (t >> 3);
    const int e = pid >> 2; ni = pid & 3;
    live = cnt[e] - mi * 256;
    if (live <= 0) return;
    if (live > 256) live = 256;
    row0 = baseA[e] + mi * 256; e18 = e;
  } else {
    id -= 384;                            // 6 exp * 8 mi * 4 ni
    const int k = id & 7, t = id >> 3;
    mi = t & 7; const int pid = k * 3 + (t >> 3);
    const int e = pid >> 2; ni = pid & 3;
    row0 = 8192L + e * 2048 + mi * 256; live = 256; e18 = 12 + e;
  }
  const int tid = threadIdx.x;
  const int srow = tid >> 2;
  const int sch = ((tid & 3) ^ ((tid >> 3) & 3)) * 8;
  const f16* pa0 = h + (row0 + srow) * 2048 + sch;
  const f16* pa1 = pa0 + 128 * 2048;
  const f16* pb0 = w2t + (long)e18 * 1024 * 2048 + ((long)ni * 256 + srow) * 2048 + sch;
  const f16* pb1 = pb0 + 128 * 2048;
  const int wave = tid >> 6, lane = tid & 63;
  const int wm = wave & 1, wn = wave >> 1;
  const int l16 = lane & 15, q = lane >> 4;
  const int qa = (q ^ ((l16 >> 1) & 3)) * 8;
  const int arow = wm * 128 + l16;
  const int brow = wn * 64 + l16;
  f32x4 acc[8][4] = {};
  f16x8 av[8], bv[2];
  ST_A(0, 0, 0) ST_B(0, 0, 0) ST_A(0, 0, 1) ST_B(0, 0, 1) ST_A(1, 1, 0) ST_B(1, 1, 0)
  WVM8(); BARX(); SB0();
#pragma unroll 1
  for (int kt = 0; kt < NKC; kt += 2) { GTILE(kt, 0) GTILE(kt + 1, 1) }
  WVM0();
#pragma unroll
  for (int i = 0; i < 8; i++) {
#pragma unroll
    for (int r = 0; r < 4; r++) {
      const int lr = wm * 128 + i * 16 + q * 4 + r;
      if (lr < live) {
        f16* C = res + (row0 + lr) * 1024 + ni * 256 + wn * 64 + l16;
#pragma unroll
        for (int jj = 0; jj < 4; jj++) C[jj * 16] = (f16)acc[i][jj][r];
      }
    }
  }
}

// ------------------------------------------------ small dense GEMM (dbuf)
// BK=64; LDS rows 128 B; chunk swizzle phys = (hf*4+q) ^ (row&7), staged via
// pre-swizzled global source (linear LDS dest), read with same involution.

struct GA {
  const f16* A; long lda;
  const f16* B; long ldb;
  int nk;                      // K / 64
  float* Cf; f16* Ch;
  const float* bias;
  const float* op; const float* om;
  const float* pt; const float* ts;
  float* pt_out; float* tsum_out;
  const float* ent; const float* tsb; float* aux_out;  // EPI==4 aux fusion
};

// BM=BN=64. EPI: 2 tanh->f16 ; 3 mod+tension ; 4 final output (+aux in block 0,0)
template <int EPI>
__global__ __launch_bounds__(256) void gemm_s(GA a) {
  __shared__ f16 Al[2][64 * 64];
  __shared__ f16 Bl[2][64 * 64];
  const int tid = threadIdx.x;
  const int wave = tid >> 6, lane = tid & 63;
  const int wm = wave & 1, wn = wave >> 1;
  const int l16 = lane & 15, q = lane >> 4;
  const long m0 = (long)blockIdx.y * 64;
  const long n0 = (long)blockIdx.x * 64;
  const int srow = tid >> 3;
  const int sch  = ((tid & 7) ^ (srow & 7)) * 8;
  const f16* a0 = a.A + (m0 + srow) * a.lda + sch;
  const f16* a1 = a.A + (m0 + srow + 32) * a.lda + sch;
  const f16* b0 = a.B + (n0 + srow) * a.ldb + sch;
  const f16* b1 = a.B + (n0 + srow + 32) * a.ldb + sch;
  const int rx = (l16 & 7) * 8;
  f32x4 acc[2][2] = {};
  LOAD_LDS16(a0, &Al[0][tid * 8]);
  LOAD_LDS16(a1, &Al[0][(256 + tid) * 8]);
  LOAD_LDS16(b0, &Bl[0][tid * 8]);
  LOAD_LDS16(b1, &Bl[0][(256 + tid) * 8]);
  for (int kk = 0; kk < a.nk; ++kk) {
    __syncthreads();
    const int cur = kk & 1;
    if (kk + 1 < a.nk) {
      const long k0 = (long)(kk + 1) * 64;
      const int nb = cur ^ 1;
      LOAD_LDS16(a0 + k0, &Al[nb][tid * 8]);
      LOAD_LDS16(a1 + k0, &Al[nb][(256 + tid) * 8]);
      LOAD_LDS16(b0 + k0, &Bl[nb][tid * 8]);
      LOAD_LDS16(b1 + k0, &Bl[nb][(256 + tid) * 8]);
    }
    f16x8 avv[2][2], bvv[2][2];
#pragma unroll
    for (int hf = 0; hf < 2; hf++) {
      const int cA = (((hf * 4 + q) * 8) ^ rx);
#pragma unroll
      for (int i = 0; i < 2; i++)
        avv[hf][i] = *(const f16x8*)&Al[cur][(wm * 32 + i * 16 + l16) * 64 + cA];
#pragma unroll
      for (int j = 0; j < 2; j++)
        bvv[hf][j] = *(const f16x8*)&Bl[cur][(wn * 32 + j * 16 + l16) * 64 + cA];
    }
#pragma unroll
    for (int hf = 0; hf < 2; hf++)
#pragma unroll
      for (int i = 0; i < 2; i++)
#pragma unroll
        for (int j = 0; j < 2; j++)
          acc[i][j] = __builtin_amdgcn_mfma_f32_16x16x32_f16(avv[hf][i], bvv[hf][j], acc[i][j], 0, 0, 0);
  }
  if constexpr (EPI == 2) {
#pragma unroll
    for (int i = 0; i < 2; i++)
#pragma unroll
      for (int r = 0; r < 4; r++) {
        const long gr = m0 + wm * 32 + i * 16 + q * 4 + r;
#pragma unroll
        for (int j = 0; j < 2; j++) {
          const int gc = (int)n0 + wn * 32 + j * 16 + l16;
          a.Ch[gr * 1024 + gc] = (f16)tanhf(acc[i][j][r] + a.bias[gc]);
        }
      }
  } else if constexpr (EPI == 3) {
    float wave_ss = 0.f;
#pragma unroll
    for (int i = 0; i < 2; i++)
#pragma unroll
      for (int r = 0; r < 4; r++) {
        const long gr = m0 + wm * 32 + i * 16 + q * 4 + r;
        float ss = 0.f;
#pragma unroll
        for (int j = 0; j < 2; j++) {
          const int gc = (int)n0 + wn * 32 + j * 16 + l16;
          const long ix = gr * 1024 + gc;
          const float v = (a.op[ix] - a.om[ix]) + acc[i][j][r] + a.bias[gc];
          a.Ch[ix] = (f16)v;
          ss += v * v;
        }
        ss += __shfl_xor(ss, 1); ss += __shfl_xor(ss, 2);
        ss += __shfl_xor(ss, 4); ss += __shfl_xor(ss, 8);
        if (l16 == 0) {
          atomicAdd(a.pt_out + gr, ss);
          wave_ss += ss;
        }
      }
    wave_ss += __shfl_xor(wave_ss, 16);
    wave_ss += __shfl_xor(wave_ss, 32);
    if (lane == 0) atomicAdd(a.tsum_out, wave_ss);
  } else {  // EPI == 4
    const float tsc = a.ts[0];
#pragma unroll
    for (int i = 0; i < 2; i++)
#pragma unroll
      for (int r = 0; r < 4; r++) {
        const long gr = m0 + wm * 32 + i * 16 + q * 4 + r;
        const float sq = sqrtf(a.pt[gr] + 1e-8f) * tsc;
#pragma unroll
        for (int j = 0; j < 2; j++) {
          const int gc = (int)n0 + wn * 32 + j * 16 + l16;
          const long ix = gr * 1024 + gc;
          const float v = tanhf(acc[i][j][r] + a.bias[gc]);
          a.Cf[ix] = 0.5f * (a.op[ix] + a.om[ix]) + sq * v;
        }
      }
    // aux loss fused into block (0,0): all tsb[0..3] were written before launch
    if (blockIdx.x == 0 && blockIdx.y == 0) {
      float s = 0.f;
      for (int i = tid; i < 2048; i += 256) s += a.ent[i];
#pragma unroll
      for (int m = 1; m < 64; m <<= 1) s += __shfl_xor(s, m);
      __shared__ float rwa[4];
      if ((tid & 63) == 0) rwa[tid >> 6] = s;
      __syncthreads();
      if (tid == 0) {
        const float hh = (rwa[0] + rwa[1] + rwa[2] + rwa[3]) * (1.f / 2048.f);
        const float dd = hh - 1.0114042647f;
        const float el = dd * dd;
        const float t0 = a.tsb[0] * (1.f / 2048.f), t1 = a.tsb[1] * (1.f / 2048.f);
        const float t2 = a.tsb[2] * (1.f / 2048.f), t3 = a.tsb[3] * (1.f / 2048.f);
        const float conv = (fabsf(t1 - t0) + fabsf(t2 - t1) + fabsf(t3 - t2)) * (1.f / 3.f);
        a.aux_out[0] = el + 0.001f * conv;
      }
    }
  }
}

// ---------------------------------------------------------------- launcher

extern "C" void kernel_launch(void* const* d_in, const int* in_sizes, int n_in,
                              void* d_out, int out_size, void* d_ws, size_t ws_size,
                              hipStream_t stream) {
  (void)in_sizes; (void)n_in; (void)out_size; (void)ws_size;
  const float* x    = (const float*)d_in[0];
  const float* gaw  = (const float*)d_in[1];
  const float* gab  = (const float*)d_in[2];
  const float* wa1  = (const float*)d_in[3];
  const float* ba1  = (const float*)d_in[4];
  const float* wa2  = (const float*)d_in[5];
  const float* ba2  = (const float*)d_in[6];
  const float* ggw  = (const float*)d_in[7];
  const float* ggb  = (const float*)d_in[8];
  const float* wg1  = (const float*)d_in[9];
  const float* bg1  = (const float*)d_in[10];
  const float* wg2  = (const float*)d_in[11];
  const float* bg2  = (const float*)d_in[12];
  const float* smw1 = (const float*)d_in[13];
  const float* smb1 = (const float*)d_in[14];
  const float* smw2 = (const float*)d_in[15];
  const float* smb2 = (const float*)d_in[16];
  const float* siw  = (const float*)d_in[17];
  const float* sib  = (const float*)d_in[18];
  const float* ftw  = (const float*)d_in[19];
  const float* ftb  = (const float*)d_in[20];
  const float* tsc  = (const float*)d_in[21];

  char* p = (char*)d_ws;
  size_t off = 0;
  auto alloc = [&](size_t bytes) -> char* {
    char* r = p + off;
    off = (off + bytes + 255) & ~(size_t)255;
    return r;
  };
  f16* xb     = (f16*)alloc(2048UL * 1024 * 2);
  f16* w1t    = (f16*)alloc(18UL * 2048 * 1024 * 2);   // later reused as w2t
  f16* smw2t  = (f16*)alloc(1024UL * 2048 * 2);
  f16* sit    = (f16*)alloc(1024UL * 1024 * 2);
  f16* ftt    = (f16*)alloc(1024UL * 1024 * 2);
  f16* h      = (f16*)alloc(20480UL * 2048 * 2);       // 8192 A-compact + 6*2048 G
  f16* res    = (f16*)alloc(20480UL * 1024 * 2);
  float* outP = (float*)alloc(2048UL * 1024 * 4);
  float* outM = (float*)alloc(2048UL * 1024 * 4);
  f16* hsmb   = (f16*)alloc(2048UL * 2048 * 2);
  f16* sst    = (f16*)alloc(2048UL * 1024 * 2);
  f16* modb   = (f16*)alloc(2048UL * 1024 * 2);
  float* entb = (float*)alloc(2048 * 4);
  float* wGb  = (float*)alloc(2048 * 6 * 4);
  float* ptb  = (float*)alloc(4 * 2048 * 4);           // 32768 B
  float* tsb  = (float*)alloc(4 * 4);                  // +32768 (rounds to 256)
  int*   cntb = (int*)alloc(12 * 4);                   // +33024
  int*   baseAb = (int*)alloc(12 * 4);
  int*   rowsb  = (int*)alloc(12 * 2048 * 4);
  float* gvalb  = (float*)alloc(12 * 2048 * 4);
  int*   eAb    = (int*)alloc(2048 * 4 * 4);
  int*   posAb  = (int*)alloc(2048 * 4 * 4);
  float* wA4b   = (float*)alloc(2048 * 4 * 4);

  f16* w2t = w1t;  // [18][1024][2048], reused after gemm1

  // zero tension accumulators + expert counters (contiguous region)
  hipMemsetAsync(ptb, 0, 33072, stream);

  // weight conversion + transpose to [N][K] fp16 (wa1+wg1 in ONE launch)
  transpose_cast2<<<dim3(64, 32, 18), 256, 0, stream>>>(wa1, wg1, 12, w1t,
      1024, 2048, 1024L * 2048, 2048L * 1024, 1024);
  // the three small transposes in ONE launch
  {
    TDesc3 td;
    td.m[0] = {smw2, smw2t, 2048, 1024, 2048};
    td.m[1] = {siw,  sit,  1024, 1024, 1024};
    td.m[2] = {ftw,  ftt,  1024, 1024, 1024};
    transpose3<<<dim3(32, 64, 3), 256, 0, stream>>>(td);
  }
  gating_kernel<<<2048, 256, 0, stream>>>(x, gaw, gab, ggw, ggb, xb, wGb, entb,
                                          rowsb, gvalb, cntb, eAb, posAb, wA4b);
  base_kernel<<<1, 64, 0, stream>>>(cntb, baseAb);

  // unified GEMM1 (A routed + G dense), 8-phase 256^2
  gemm1_kernel<<<1152, 512, 0, stream>>>(xb, w1t, ba1, bg1, h,
                                         rowsb, gvalb, cntb, baseAb, wGb);

  // layer-2 weights into the (now dead) w1t region (wa2+wg2 in ONE launch)
  transpose_cast2<<<dim3(32, 64, 18), 256, 0, stream>>>(wa2, wg2, 12, w2t,
      2048, 1024, 2048L * 1024, 1024L * 2048, 2048);

  // unified GEMM2, 8-phase 256^2, compact f16 out, no atomics
  gemm2_kernel<<<576, 512, 0, stream>>>(h, w2t, res, cntb, baseAb);

  combine_kernel<<<2048, 256, 0, stream>>>(res, eAb, posAb, wA4b, wGb, baseAb,
                                           ba2, bg2, outP, outM, ptb, tsb);

  for (int s = 0; s < 3; s++) {
    hsm_kernel<<<dim3(8, 32), 256, 0, stream>>>(ptb + s * 2048, tsb + s, smw1, smb1, hsmb, s);
    GA g3{};
    g3.A = hsmb; g3.lda = 2048; g3.B = smw2t; g3.ldb = 2048; g3.nk = 32;
    g3.Ch = sst; g3.bias = smb2;
    gemm_s<2><<<dim3(16, 32), 256, 0, stream>>>(g3);
    GA g4{};
    g4.A = sst; g4.lda = 1024; g4.B = sit; g4.ldb = 1024; g4.nk = 16;
    g4.Ch = modb; g4.bias = sib; g4.op = outP; g4.om = outM;
    g4.pt_out = ptb + (s + 1) * 2048; g4.tsum_out = tsb + (s + 1);
    gemm_s<3><<<dim3(16, 32), 256, 0, stream>>>(g4);
  }

  GA g5{};
  g5.A = modb; g5.lda = 1024; g5.B = ftt; g5.ldb = 1024; g5.nk = 16;
  g5.Cf = (float*)d_out; g5.bias = ftb; g5.op = outP; g5.om = outM;
  g5.pt = ptb + 3 * 2048; g5.ts = tsc;
  g5.ent = entb; g5.tsb = tsb; g5.aux_out = (float*)d_out + 2048UL * 1024;
  gemm_s<4><<<dim3(16, 32), 256, 0, stream>>>(g5);
}